// Round 1
// baseline (3601.622 us; speedup 1.0000x reference)
//
#include <hip/hip_runtime.h>
#include <math.h>

#define NN 50000
#define NE 800000
#define DIN 128
#define DHID 128
#define DOUT 64
#define BN_EPS 1e-5f

// ---------------------------------------------------------------------------
// Scatter x[src] into msg[dst] (sum) + count in-degree. One thread = (edge, 4 feats).
__global__ __launch_bounds__(256) void k_scatter_x(
    const float* __restrict__ x, const int* __restrict__ ei,
    float* __restrict__ msg, float* __restrict__ cnt)
{
    long long t = (long long)blockIdx.x * blockDim.x + threadIdx.x;
    if (t >= (long long)NE * 32) return;
    int e = (int)(t >> 5);
    int g = ((int)t & 31) << 2;
    int src = ei[e];
    int dst = ei[NE + e];
    float4 v = *(const float4*)(x + (size_t)src * DIN + g);
    float* m = msg + (size_t)dst * DIN + g;
    atomicAdd(m + 0, v.x);
    atomicAdd(m + 1, v.y);
    atomicAdd(m + 2, v.z);
    atomicAdd(m + 3, v.w);
    if ((t & 31) == 0) atomicAdd(cnt + dst, 1.0f);
}

// Scatter h[src] into msg[dst] (sum). One thread = (edge, 4 feats).
__global__ __launch_bounds__(256) void k_scatter_h(
    const float* __restrict__ h, const int* __restrict__ ei,
    float* __restrict__ msg)
{
    long long t = (long long)blockIdx.x * blockDim.x + threadIdx.x;
    if (t >= (long long)NE * 32) return;
    int e = (int)(t >> 5);
    int g = ((int)t & 31) << 2;
    int src = ei[e];
    int dst = ei[NE + e];
    float4 v = *(const float4*)(h + (size_t)src * DHID + g);
    float* m = msg + (size_t)dst * DHID + g;
    atomicAdd(m + 0, v.x);
    atomicAdd(m + 1, v.y);
    atomicAdd(m + 2, v.z);
    atomicAdd(m + 3, v.w);
}

// ---------------------------------------------------------------------------
// Conv1: h = relu(BN(mean @ Wl.T + bl + x @ Wr.T))
// Wave-uniform output chunk (32 cols), lane = row. acc[] statically indexed.
__global__ __launch_bounds__(256) void k_conv1(
    const float* __restrict__ x, const float* __restrict__ msg, const float* __restrict__ cnt,
    const float* __restrict__ Wl, const float* __restrict__ bl, const float* __restrict__ Wr,
    const float* __restrict__ gam, const float* __restrict__ bet,
    const float* __restrict__ bmean, const float* __restrict__ bvar,
    float* __restrict__ h)
{
    int t = blockIdx.x * blockDim.x + threadIdx.x;
    int wv = t >> 6, lane = t & 63;
    int chunk = wv & 3;          // wave-uniform: which 32-col chunk
    int rb = wv >> 2;
    int r = rb * 64 + lane;
    if (r >= NN) return;
    int jc = chunk * 32;

    float inv = 1.0f / fmaxf(cnt[r], 1.0f);
    const float4* xr = (const float4*)(x + (size_t)r * DIN);
    const float4* mr = (const float4*)(msg + (size_t)r * DIN);

    float acc[32];
    #pragma unroll
    for (int j = 0; j < 32; ++j) acc[j] = bl[jc + j];

    for (int kb = 0; kb < DIN / 4; ++kb) {
        float4 m4 = mr[kb];
        float4 x4 = xr[kb];
        m4.x *= inv; m4.y *= inv; m4.z *= inv; m4.w *= inv;
        #pragma unroll
        for (int j = 0; j < 32; ++j) {
            const float* wl = Wl + (size_t)(jc + j) * DIN + kb * 4;   // wave-uniform addr
            const float* wr = Wr + (size_t)(jc + j) * DIN + kb * 4;   // wave-uniform addr
            acc[j] += m4.x * wl[0] + m4.y * wl[1] + m4.z * wl[2] + m4.w * wl[3]
                    + x4.x * wr[0] + x4.y * wr[1] + x4.z * wr[2] + x4.w * wr[3];
        }
    }

    float4 ov;
    #pragma unroll
    for (int jj = 0; jj < 8; ++jj) {
        float tmp[4];
        #pragma unroll
        for (int q = 0; q < 4; ++q) {
            int col = jc + jj * 4 + q;
            float v = (acc[jj * 4 + q] - bmean[col]) * rsqrtf(bvar[col] + BN_EPS) * gam[col] + bet[col];
            tmp[q] = fmaxf(v, 0.0f);
        }
        ov.x = tmp[0]; ov.y = tmp[1]; ov.z = tmp[2]; ov.w = tmp[3];
        *(float4*)(h + (size_t)r * DHID + jc + jj * 4) = ov;
    }
}

// Conv2: z = mean2 @ Wl.T + bl + h @ Wr.T   (no BN/relu)
__global__ __launch_bounds__(256) void k_conv2(
    const float* __restrict__ h, const float* __restrict__ msg, const float* __restrict__ cnt,
    const float* __restrict__ Wl, const float* __restrict__ bl, const float* __restrict__ Wr,
    float* __restrict__ z)
{
    int t = blockIdx.x * blockDim.x + threadIdx.x;
    int wv = t >> 6, lane = t & 63;
    int chunk = wv & 1;          // wave-uniform: which 32-col chunk of 64
    int rb = wv >> 1;
    int r = rb * 64 + lane;
    if (r >= NN) return;
    int jc = chunk * 32;

    float inv = 1.0f / fmaxf(cnt[r], 1.0f);
    const float4* hr = (const float4*)(h + (size_t)r * DHID);
    const float4* mr = (const float4*)(msg + (size_t)r * DHID);

    float acc[32];
    #pragma unroll
    for (int j = 0; j < 32; ++j) acc[j] = bl[jc + j];

    for (int kb = 0; kb < DHID / 4; ++kb) {
        float4 m4 = mr[kb];
        float4 h4 = hr[kb];
        m4.x *= inv; m4.y *= inv; m4.z *= inv; m4.w *= inv;
        #pragma unroll
        for (int j = 0; j < 32; ++j) {
            const float* wl = Wl + (size_t)(jc + j) * DHID + kb * 4;
            const float* wr = Wr + (size_t)(jc + j) * DHID + kb * 4;
            acc[j] += m4.x * wl[0] + m4.y * wl[1] + m4.z * wl[2] + m4.w * wl[3]
                    + h4.x * wr[0] + h4.y * wr[1] + h4.z * wr[2] + h4.w * wr[3];
        }
    }

    #pragma unroll
    for (int jj = 0; jj < 8; ++jj) {
        float4 ov;
        ov.x = acc[jj * 4 + 0];
        ov.y = acc[jj * 4 + 1];
        ov.z = acc[jj * 4 + 2];
        ov.w = acc[jj * 4 + 3];
        *(float4*)(z + (size_t)r * DOUT + jc + jj * 4) = ov;
    }
}

// ---------------------------------------------------------------------------
// Edge head: out = sigmoid(relu(relu([zi,zj]@W1.T+b1)@W2.T+b2)@W3.T+b3)
// One thread per edge; all register arrays statically indexed (rule #20).
__global__ __launch_bounds__(256) void k_edge(
    const float* __restrict__ z, const int* __restrict__ ep,
    const float* __restrict__ W1, const float* __restrict__ b1,
    const float* __restrict__ W2, const float* __restrict__ b2,
    const float* __restrict__ W3, const float* __restrict__ b3,
    float* __restrict__ out)
{
    int p = blockIdx.x * blockDim.x + threadIdx.x;
    if (p >= NE) return;
    int ni = ep[p];
    int nj = ep[NE + p];
    const float4* zi = (const float4*)(z + (size_t)ni * DOUT);
    const float4* zj = (const float4*)(z + (size_t)nj * DOUT);

    float a1[64];
    #pragma unroll
    for (int q = 0; q < 64; ++q) a1[q] = b1[q];

    for (int kb = 0; kb < 16; ++kb) {             // first half: zi, k = kb*4
        float4 v = zi[kb];
        #pragma unroll
        for (int q = 0; q < 64; ++q) {
            const float* w = W1 + (size_t)q * 128 + kb * 4;    // wave-uniform
            a1[q] += v.x * w[0] + v.y * w[1] + v.z * w[2] + v.w * w[3];
        }
    }
    for (int kb = 0; kb < 16; ++kb) {             // second half: zj, k = 64 + kb*4
        float4 v = zj[kb];
        #pragma unroll
        for (int q = 0; q < 64; ++q) {
            const float* w = W1 + (size_t)q * 128 + 64 + kb * 4;
            a1[q] += v.x * w[0] + v.y * w[1] + v.z * w[2] + v.w * w[3];
        }
    }

    float a2[32];
    #pragma unroll
    for (int q = 0; q < 32; ++q) a2[q] = b2[q];
    #pragma unroll
    for (int k = 0; k < 64; ++k) {                // fully unrolled: a1[k] static
        float e = fmaxf(a1[k], 0.0f);
        #pragma unroll
        for (int q = 0; q < 32; ++q) {
            a2[q] += e * W2[(size_t)q * 64 + k];
        }
    }

    float t3 = b3[0];
    #pragma unroll
    for (int k = 0; k < 32; ++k) {
        t3 += fmaxf(a2[k], 0.0f) * W3[k];
    }
    out[p] = 1.0f / (1.0f + expf(-t3));
}

// ---------------------------------------------------------------------------
extern "C" void kernel_launch(void* const* d_in, const int* in_sizes, int n_in,
                              void* d_out, int out_size, void* d_ws, size_t ws_size,
                              hipStream_t stream)
{
    const float* x     = (const float*)d_in[0];
    const int*   ei    = (const int*)d_in[1];
    const int*   ep    = (const int*)d_in[2];
    const float* c1_Wl = (const float*)d_in[3];
    const float* c1_bl = (const float*)d_in[4];
    const float* c1_Wr = (const float*)d_in[5];
    const float* bn_g  = (const float*)d_in[6];
    const float* bn_b  = (const float*)d_in[7];
    const float* bn_m  = (const float*)d_in[8];
    const float* bn_v  = (const float*)d_in[9];
    const float* c2_Wl = (const float*)d_in[10];
    const float* c2_bl = (const float*)d_in[11];
    const float* c2_Wr = (const float*)d_in[12];
    const float* e_W1  = (const float*)d_in[13];
    const float* e_b1  = (const float*)d_in[14];
    const float* e_W2  = (const float*)d_in[15];
    const float* e_b2  = (const float*)d_in[16];
    const float* e_W3  = (const float*)d_in[17];
    const float* e_b3  = (const float*)d_in[18];
    float* out = (float*)d_out;

    // workspace layout (f32): msg[N*128] | cnt[N] | h[N*128] | z[N*64]
    float* msg = (float*)d_ws;
    float* cnt = msg + (size_t)NN * DIN;
    float* h   = cnt + NN;
    float* z   = h + (size_t)NN * DHID;

    // zero msg + cnt (contiguous)
    hipMemsetAsync(msg, 0, ((size_t)NN * DIN + NN) * sizeof(float), stream);

    k_scatter_x<<<100000, 256, 0, stream>>>(x, ei, msg, cnt);
    k_conv1<<<782, 256, 0, stream>>>(x, msg, cnt, c1_Wl, c1_bl, c1_Wr,
                                     bn_g, bn_b, bn_m, bn_v, h);

    // reuse msg buffer for second aggregation
    hipMemsetAsync(msg, 0, (size_t)NN * DHID * sizeof(float), stream);
    k_scatter_h<<<100000, 256, 0, stream>>>(h, ei, msg);
    k_conv2<<<391, 256, 0, stream>>>(h, msg, cnt, c2_Wl, c2_bl, c2_Wr, z);

    k_edge<<<3125, 256, 0, stream>>>(z, ep, e_W1, e_b1, e_W2, e_b2,
                                     e_W3, e_b3, out);
}

// Round 2
// 1877.915 us; speedup vs baseline: 1.9179x; 1.9179x over previous
//
#include <hip/hip_runtime.h>
#include <math.h>

#define NN 50000
#define NE 800000
#define DIN 128
#define DHID 128
#define DOUT 64
#define BN_EPS 1e-5f

// ---------------------------------------------------------------------------
// CSR build: histogram of dst degrees.
__global__ __launch_bounds__(256) void k_deg(const int* __restrict__ ei, int* __restrict__ deg)
{
    int e = blockIdx.x * blockDim.x + threadIdx.x;
    if (e >= NE) return;
    atomicAdd(deg + ei[NE + e], 1);
}

// Exclusive prefix sum over deg[NN] -> rowptr[NN+1]. Single block, 256 threads.
__global__ __launch_bounds__(256) void k_scan(const int* __restrict__ deg, int* __restrict__ rowptr)
{
    __shared__ int part[256];
    const int CH = (NN + 255) / 256;   // 196
    int t = threadIdx.x;
    int beg = t * CH;
    int end = beg + CH < NN ? beg + CH : NN;
    int s = 0;
    for (int i = beg; i < end; ++i) s += deg[i];
    part[t] = s;
    __syncthreads();
    if (t == 0) {
        int acc = 0;
        for (int i = 0; i < 256; ++i) { int v = part[i]; part[i] = acc; acc += v; }
    }
    __syncthreads();
    int run = part[t];
    for (int i = beg; i < end; ++i) { rowptr[i] = run; run += deg[i]; }
    if (t == 255) rowptr[NN] = NE;
}

// Fill CSR column (src) array.
__global__ __launch_bounds__(256) void k_fill(
    const int* __restrict__ ei, const int* __restrict__ rowptr,
    int* __restrict__ cursor, int* __restrict__ csr_src)
{
    int e = blockIdx.x * blockDim.x + threadIdx.x;
    if (e >= NE) return;
    int dst = ei[NE + e];
    int slot = atomicAdd(cursor + dst, 1);
    csr_src[rowptr[dst] + slot] = ei[e];
}

// ---------------------------------------------------------------------------
// Gather-mean over CSR: one wave per node, lane owns 2 feats (D=128 fixed).
__global__ __launch_bounds__(256) void k_gather_mean(
    const float* __restrict__ feat, const int* __restrict__ rowptr,
    const int* __restrict__ csr_src, float* __restrict__ mean)
{
    int wv = (blockIdx.x * blockDim.x + threadIdx.x) >> 6;
    int lane = threadIdx.x & 63;
    if (wv >= NN) return;
    int beg = rowptr[wv], end = rowptr[wv + 1];

    float2 a0 = {0.f, 0.f}, a1 = {0.f, 0.f};
    int j = beg;
    for (; j + 1 < end; j += 2) {
        int s0 = csr_src[j];
        int s1 = csr_src[j + 1];
        float2 v0 = *(const float2*)(feat + (size_t)s0 * 128 + lane * 2);
        float2 v1 = *(const float2*)(feat + (size_t)s1 * 128 + lane * 2);
        a0.x += v0.x; a0.y += v0.y;
        a1.x += v1.x; a1.y += v1.y;
    }
    if (j < end) {
        int s0 = csr_src[j];
        float2 v0 = *(const float2*)(feat + (size_t)s0 * 128 + lane * 2);
        a0.x += v0.x; a0.y += v0.y;
    }
    float inv = 1.0f / fmaxf((float)(end - beg), 1.0f);
    float2 o = { (a0.x + a1.x) * inv, (a0.y + a1.y) * inv };
    *(float2*)(mean + (size_t)wv * 128 + lane * 2) = o;
}

// ---------------------------------------------------------------------------
// Conv1: h = relu(BN(mean @ Wl.T + bl + x @ Wr.T))
__global__ __launch_bounds__(256) void k_conv1(
    const float* __restrict__ x, const float* __restrict__ mean,
    const float* __restrict__ Wl, const float* __restrict__ bl, const float* __restrict__ Wr,
    const float* __restrict__ gam, const float* __restrict__ bet,
    const float* __restrict__ bmean, const float* __restrict__ bvar,
    float* __restrict__ h)
{
    int t = blockIdx.x * blockDim.x + threadIdx.x;
    int wv = t >> 6, lane = t & 63;
    int chunk = wv & 3;          // wave-uniform 32-col chunk
    int rb = wv >> 2;
    int r = rb * 64 + lane;
    if (r >= NN) return;
    int jc = chunk * 32;

    const float4* xr = (const float4*)(x + (size_t)r * DIN);
    const float4* mr = (const float4*)(mean + (size_t)r * DIN);

    float acc[32];
    #pragma unroll
    for (int j = 0; j < 32; ++j) acc[j] = bl[jc + j];

    for (int kb = 0; kb < DIN / 4; ++kb) {
        float4 m4 = mr[kb];
        float4 x4 = xr[kb];
        #pragma unroll
        for (int j = 0; j < 32; ++j) {
            const float* wl = Wl + (size_t)(jc + j) * DIN + kb * 4;   // wave-uniform
            const float* wr = Wr + (size_t)(jc + j) * DIN + kb * 4;
            acc[j] += m4.x * wl[0] + m4.y * wl[1] + m4.z * wl[2] + m4.w * wl[3]
                    + x4.x * wr[0] + x4.y * wr[1] + x4.z * wr[2] + x4.w * wr[3];
        }
    }

    #pragma unroll
    for (int jj = 0; jj < 8; ++jj) {
        float4 ov;
        float tmp[4];
        #pragma unroll
        for (int q = 0; q < 4; ++q) {
            int col = jc + jj * 4 + q;
            float v = (acc[jj * 4 + q] - bmean[col]) * rsqrtf(bvar[col] + BN_EPS) * gam[col] + bet[col];
            tmp[q] = fmaxf(v, 0.0f);
        }
        ov.x = tmp[0]; ov.y = tmp[1]; ov.z = tmp[2]; ov.w = tmp[3];
        *(float4*)(h + (size_t)r * DHID + jc + jj * 4) = ov;
    }
}

// Conv2: z = mean2 @ Wl.T + bl + h @ Wr.T
__global__ __launch_bounds__(256) void k_conv2(
    const float* __restrict__ h, const float* __restrict__ mean,
    const float* __restrict__ Wl, const float* __restrict__ bl, const float* __restrict__ Wr,
    float* __restrict__ z)
{
    int t = blockIdx.x * blockDim.x + threadIdx.x;
    int wv = t >> 6, lane = t & 63;
    int chunk = wv & 1;
    int rb = wv >> 1;
    int r = rb * 64 + lane;
    if (r >= NN) return;
    int jc = chunk * 32;

    const float4* hr = (const float4*)(h + (size_t)r * DHID);
    const float4* mr = (const float4*)(mean + (size_t)r * DHID);

    float acc[32];
    #pragma unroll
    for (int j = 0; j < 32; ++j) acc[j] = bl[jc + j];

    for (int kb = 0; kb < DHID / 4; ++kb) {
        float4 m4 = mr[kb];
        float4 h4 = hr[kb];
        #pragma unroll
        for (int j = 0; j < 32; ++j) {
            const float* wl = Wl + (size_t)(jc + j) * DHID + kb * 4;
            const float* wr = Wr + (size_t)(jc + j) * DHID + kb * 4;
            acc[j] += m4.x * wl[0] + m4.y * wl[1] + m4.z * wl[2] + m4.w * wl[3]
                    + h4.x * wr[0] + h4.y * wr[1] + h4.z * wr[2] + h4.w * wr[3];
        }
    }

    #pragma unroll
    for (int jj = 0; jj < 8; ++jj) {
        float4 ov;
        ov.x = acc[jj * 4 + 0];
        ov.y = acc[jj * 4 + 1];
        ov.z = acc[jj * 4 + 2];
        ov.w = acc[jj * 4 + 3];
        *(float4*)(z + (size_t)r * DOUT + jc + jj * 4) = ov;
    }
}

// ---------------------------------------------------------------------------
// Edge head, chunked to avoid register spill: 16 L1 neurons per chunk,
// immediately folded into a2[32]. z rows re-read per chunk (L1-resident).
__global__ __launch_bounds__(256) void k_edge(
    const float* __restrict__ z, const int* __restrict__ ep,
    const float* __restrict__ W1, const float* __restrict__ b1,
    const float* __restrict__ W2, const float* __restrict__ b2,
    const float* __restrict__ W3, const float* __restrict__ b3,
    float* __restrict__ out)
{
    int p = blockIdx.x * blockDim.x + threadIdx.x;
    if (p >= NE) return;
    int ni = ep[p];
    int nj = ep[NE + p];
    const float4* zi = (const float4*)(z + (size_t)ni * DOUT);
    const float4* zj = (const float4*)(z + (size_t)nj * DOUT);

    float a2[32];
    #pragma unroll
    for (int o = 0; o < 32; ++o) a2[o] = b2[o];

    #pragma unroll 1
    for (int c = 0; c < 4; ++c) {
        float tacc[16];
        #pragma unroll
        for (int q = 0; q < 16; ++q) tacc[q] = b1[c * 16 + q];

        #pragma unroll
        for (int kb = 0; kb < 16; ++kb) {
            float4 v = zi[kb];
            #pragma unroll
            for (int q = 0; q < 16; ++q) {
                const float* w = W1 + (size_t)(c * 16 + q) * 128 + kb * 4;  // wave-uniform
                tacc[q] += v.x * w[0] + v.y * w[1] + v.z * w[2] + v.w * w[3];
            }
        }
        #pragma unroll
        for (int kb = 0; kb < 16; ++kb) {
            float4 v = zj[kb];
            #pragma unroll
            for (int q = 0; q < 16; ++q) {
                const float* w = W1 + (size_t)(c * 16 + q) * 128 + 64 + kb * 4;
                tacc[q] += v.x * w[0] + v.y * w[1] + v.z * w[2] + v.w * w[3];
            }
        }

        float e[16];
        #pragma unroll
        for (int q = 0; q < 16; ++q) e[q] = fmaxf(tacc[q], 0.0f);

        #pragma unroll
        for (int o = 0; o < 32; ++o) {
            const float* w = W2 + (size_t)o * 64 + c * 16;   // wave-uniform
            float s = 0.f;
            #pragma unroll
            for (int q = 0; q < 16; ++q) s += e[q] * w[q];
            a2[o] += s;
        }
    }

    float t3 = b3[0];
    #pragma unroll
    for (int k = 0; k < 32; ++k) t3 += fmaxf(a2[k], 0.0f) * W3[k];
    out[p] = 1.0f / (1.0f + expf(-t3));
}

// ---------------------------------------------------------------------------
extern "C" void kernel_launch(void* const* d_in, const int* in_sizes, int n_in,
                              void* d_out, int out_size, void* d_ws, size_t ws_size,
                              hipStream_t stream)
{
    const float* x     = (const float*)d_in[0];
    const int*   ei    = (const int*)d_in[1];
    const int*   ep    = (const int*)d_in[2];
    const float* c1_Wl = (const float*)d_in[3];
    const float* c1_bl = (const float*)d_in[4];
    const float* c1_Wr = (const float*)d_in[5];
    const float* bn_g  = (const float*)d_in[6];
    const float* bn_b  = (const float*)d_in[7];
    const float* bn_m  = (const float*)d_in[8];
    const float* bn_v  = (const float*)d_in[9];
    const float* c2_Wl = (const float*)d_in[10];
    const float* c2_bl = (const float*)d_in[11];
    const float* c2_Wr = (const float*)d_in[12];
    const float* e_W1  = (const float*)d_in[13];
    const float* e_b1  = (const float*)d_in[14];
    const float* e_W2  = (const float*)d_in[15];
    const float* e_b2  = (const float*)d_in[16];
    const float* e_W3  = (const float*)d_in[17];
    const float* e_b3  = (const float*)d_in[18];
    float* out = (float*)d_out;

    // ws layout (floats): mean[N*128] | h[N*128] | z[N*64]
    // CSR int arrays alias the z region (dead until conv2 writes z).
    float* mean = (float*)d_ws;
    float* h    = mean + (size_t)NN * DIN;        // 6.4M floats
    float* z    = h    + (size_t)NN * DHID;       // 3.2M floats
    int* deg     = (int*)z;
    int* cursor  = deg + 50048;
    int* rowptr  = cursor + 50048;
    int* csr_src = rowptr + 50052;                 // 800000 ints; all < 3.2M floats

    // zero deg + cursor (contiguous)
    hipMemsetAsync(deg, 0, (size_t)(50048 * 2) * sizeof(int), stream);

    k_deg <<<3125, 256, 0, stream>>>(ei, deg);
    k_scan<<<1, 256, 0, stream>>>(deg, rowptr);
    k_fill<<<3125, 256, 0, stream>>>(ei, rowptr, cursor, csr_src);

    k_gather_mean<<<12500, 256, 0, stream>>>(x, rowptr, csr_src, mean);
    k_conv1<<<782, 256, 0, stream>>>(x, mean, c1_Wl, c1_bl, c1_Wr,
                                     bn_g, bn_b, bn_m, bn_v, h);

    k_gather_mean<<<12500, 256, 0, stream>>>(h, rowptr, csr_src, mean);
    k_conv2<<<391, 256, 0, stream>>>(h, mean, c2_Wl, c2_bl, c2_Wr, z);

    k_edge<<<3125, 256, 0, stream>>>(z, ep, e_W1, e_b1, e_W2, e_b2,
                                     e_W3, e_b3, out);
}

// Round 4
// 769.864 us; speedup vs baseline: 4.6783x; 2.4393x over previous
//
#include <hip/hip_runtime.h>
#include <math.h>

#define NN 50000
#define NE 800000
#define DIN 128
#define DHID 128
#define DOUT 64
#define BN_EPS 1e-5f

typedef __attribute__((ext_vector_type(8))) short bf16x8;
typedef __attribute__((ext_vector_type(4))) float f32x4;
typedef unsigned short ushort_t;
typedef unsigned int uint_t;

__device__ __forceinline__ ushort_t f2bf(float f) {
    uint_t u = __float_as_uint(f);
    uint_t r = (u + 0x7FFFu + ((u >> 16) & 1u)) >> 16;   // round-to-nearest-even
    return (ushort_t)r;
}

// ---------------------------------------------------------------------------
// CSR build: histogram of dst degrees.
__global__ __launch_bounds__(256) void k_deg(const int* __restrict__ ei, int* __restrict__ deg)
{
    int e = blockIdx.x * blockDim.x + threadIdx.x;
    if (e >= NE) return;
    atomicAdd(deg + ei[NE + e], 1);
}

// Exclusive prefix sum over deg[NN] -> rowptr[NN+1]. Single block, 256 threads.
__global__ __launch_bounds__(256) void k_scan(const int* __restrict__ deg, int* __restrict__ rowptr)
{
    __shared__ int part[256];
    const int CH = (NN + 255) / 256;
    int t = threadIdx.x;
    int beg = t * CH;
    int end = beg + CH < NN ? beg + CH : NN;
    int s = 0;
    for (int i = beg; i < end; ++i) s += deg[i];
    part[t] = s;
    __syncthreads();
    if (t == 0) {
        int acc = 0;
        for (int i = 0; i < 256; ++i) { int v = part[i]; part[i] = acc; acc += v; }
    }
    __syncthreads();
    int run = part[t];
    for (int i = beg; i < end; ++i) { rowptr[i] = run; run += deg[i]; }
    if (t == 255) rowptr[NN] = NE;
}

// Fill CSR column (src) array.
__global__ __launch_bounds__(256) void k_fill(
    const int* __restrict__ ei, const int* __restrict__ rowptr,
    int* __restrict__ cursor, int* __restrict__ csr_src)
{
    int e = blockIdx.x * blockDim.x + threadIdx.x;
    if (e >= NE) return;
    int dst = ei[NE + e];
    int slot = atomicAdd(cursor + dst, 1);
    csr_src[rowptr[dst] + slot] = ei[e];
}

// ---------------------------------------------------------------------------
// Gather-mean over CSR: one wave per node, lane owns 2 feats (D=128 fixed).
__global__ __launch_bounds__(256) void k_gather_mean(
    const float* __restrict__ feat, const int* __restrict__ rowptr,
    const int* __restrict__ csr_src, float* __restrict__ mean)
{
    int wv = (blockIdx.x * blockDim.x + threadIdx.x) >> 6;
    int lane = threadIdx.x & 63;
    if (wv >= NN) return;
    int beg = rowptr[wv], end = rowptr[wv + 1];

    float2 a0 = {0.f, 0.f}, a1 = {0.f, 0.f};
    int j = beg;
    for (; j + 1 < end; j += 2) {
        int s0 = csr_src[j];
        int s1 = csr_src[j + 1];
        float2 v0 = *(const float2*)(feat + (size_t)s0 * 128 + lane * 2);
        float2 v1 = *(const float2*)(feat + (size_t)s1 * 128 + lane * 2);
        a0.x += v0.x; a0.y += v0.y;
        a1.x += v1.x; a1.y += v1.y;
    }
    if (j < end) {
        int s0 = csr_src[j];
        float2 v0 = *(const float2*)(feat + (size_t)s0 * 128 + lane * 2);
        a0.x += v0.x; a0.y += v0.y;
    }
    float inv = 1.0f / fmaxf((float)(end - beg), 1.0f);
    float2 o = { (a0.x + a1.x) * inv, (a0.y + a1.y) * inv };
    *(float2*)(mean + (size_t)wv * 128 + lane * 2) = o;
}

// ---------------------------------------------------------------------------
// Conv1: h = relu(BN(mean @ Wl.T + bl + x @ Wr.T))
__global__ __launch_bounds__(256) void k_conv1(
    const float* __restrict__ x, const float* __restrict__ mean,
    const float* __restrict__ Wl, const float* __restrict__ bl, const float* __restrict__ Wr,
    const float* __restrict__ gam, const float* __restrict__ bet,
    const float* __restrict__ bmean, const float* __restrict__ bvar,
    float* __restrict__ h)
{
    int t = blockIdx.x * blockDim.x + threadIdx.x;
    int wv = t >> 6, lane = t & 63;
    int chunk = wv & 3;
    int rb = wv >> 2;
    int r = rb * 64 + lane;
    if (r >= NN) return;
    int jc = chunk * 32;

    const float4* xr = (const float4*)(x + (size_t)r * DIN);
    const float4* mr = (const float4*)(mean + (size_t)r * DIN);

    float acc[32];
    #pragma unroll
    for (int j = 0; j < 32; ++j) acc[j] = bl[jc + j];

    for (int kb = 0; kb < DIN / 4; ++kb) {
        float4 m4 = mr[kb];
        float4 x4 = xr[kb];
        #pragma unroll
        for (int j = 0; j < 32; ++j) {
            const float* wl = Wl + (size_t)(jc + j) * DIN + kb * 4;
            const float* wr = Wr + (size_t)(jc + j) * DIN + kb * 4;
            acc[j] += m4.x * wl[0] + m4.y * wl[1] + m4.z * wl[2] + m4.w * wl[3]
                    + x4.x * wr[0] + x4.y * wr[1] + x4.z * wr[2] + x4.w * wr[3];
        }
    }

    #pragma unroll
    for (int jj = 0; jj < 8; ++jj) {
        float4 ov;
        float tmp[4];
        #pragma unroll
        for (int q = 0; q < 4; ++q) {
            int col = jc + jj * 4 + q;
            float v = (acc[jj * 4 + q] - bmean[col]) * rsqrtf(bvar[col] + BN_EPS) * gam[col] + bet[col];
            tmp[q] = fmaxf(v, 0.0f);
        }
        ov.x = tmp[0]; ov.y = tmp[1]; ov.z = tmp[2]; ov.w = tmp[3];
        *(float4*)(h + (size_t)r * DHID + jc + jj * 4) = ov;
    }
}

// Conv2: z = mean2 @ Wl.T + bl + h @ Wr.T  -> stored directly as bf16
__global__ __launch_bounds__(256) void k_conv2(
    const float* __restrict__ h, const float* __restrict__ mean,
    const float* __restrict__ Wl, const float* __restrict__ bl, const float* __restrict__ Wr,
    ushort_t* __restrict__ zbf)
{
    int t = blockIdx.x * blockDim.x + threadIdx.x;
    int wv = t >> 6, lane = t & 63;
    int chunk = wv & 1;
    int rb = wv >> 1;
    int r = rb * 64 + lane;
    if (r >= NN) return;
    int jc = chunk * 32;

    const float4* hr = (const float4*)(h + (size_t)r * DHID);
    const float4* mr = (const float4*)(mean + (size_t)r * DHID);

    float acc[32];
    #pragma unroll
    for (int j = 0; j < 32; ++j) acc[j] = bl[jc + j];

    for (int kb = 0; kb < DHID / 4; ++kb) {
        float4 m4 = mr[kb];
        float4 h4 = hr[kb];
        #pragma unroll
        for (int j = 0; j < 32; ++j) {
            const float* wl = Wl + (size_t)(jc + j) * DHID + kb * 4;
            const float* wr = Wr + (size_t)(jc + j) * DHID + kb * 4;
            acc[j] += m4.x * wl[0] + m4.y * wl[1] + m4.z * wl[2] + m4.w * wl[3]
                    + h4.x * wr[0] + h4.y * wr[1] + h4.z * wr[2] + h4.w * wr[3];
        }
    }

    uint_t pk[16];
    #pragma unroll
    for (int q = 0; q < 16; ++q)
        pk[q] = (uint_t)f2bf(acc[2 * q]) | ((uint_t)f2bf(acc[2 * q + 1]) << 16);

    uint4* dst = (uint4*)(zbf + (size_t)r * DOUT + jc);
    #pragma unroll
    for (int q = 0; q < 4; ++q)
        dst[q] = make_uint4(pk[4 * q], pk[4 * q + 1], pk[4 * q + 2], pk[4 * q + 3]);
}

// ---------------------------------------------------------------------------
// Convert W1 (64x128 f32) and W2 (32x64 f32) to bf16 row-major.
__global__ __launch_bounds__(256) void k_prep(
    const float* __restrict__ W1, const float* __restrict__ W2,
    ushort_t* __restrict__ w1bf, ushort_t* __restrict__ w2bf)
{
    for (int i = threadIdx.x; i < 64 * 128; i += 256) w1bf[i] = f2bf(W1[i]);
    for (int i = threadIdx.x; i < 32 * 64; i += 256) w2bf[i] = f2bf(W2[i]);
}

// ---------------------------------------------------------------------------
// Edge head via MFMA, 16 edges per wave-tile.
// Layer1 (swapped): D1[n][e] = W1 . [zi|zj]^T  (16 mfma, W1 frags VGPR-resident)
// C/D layout (m89-verified): col = lane&15 = edge, row = (lane>>4)*4+reg = neuron.
// relu -> bf16 -> per-wave LDS [16e][64n], XOR swizzle off^=(e&7)<<4 (2-way = free).
// Layer2: D2[o][e] = W2 . relu(a1) (4 mfma). Layer3: VALU + shfl_xor reduce.
__global__ __launch_bounds__(256, 2) void k_edge(
    const ushort_t* __restrict__ zbf, const int* __restrict__ ep,
    const ushort_t* __restrict__ w1bf, const float* __restrict__ b1,
    const ushort_t* __restrict__ w2bf, const float* __restrict__ b2,
    const float* __restrict__ W3, const float* __restrict__ b3,
    float* __restrict__ out)
{
    __shared__ ushort_t a1lds[4][16 * 64];   // 2 KB per wave
    const int tid  = threadIdx.x;
    const int lane = tid & 63;
    const int e    = lane & 15;
    const int c    = lane >> 4;
    ushort_t* lds  = &a1lds[tid >> 6][0];
    const uint_t swz = (uint_t)((e & 7) << 4);

    // hoisted weight fragments (wave-resident across the tile loop)
    bf16x8 w1f[4][4];
    #pragma unroll
    for (int mt = 0; mt < 4; ++mt)
        #pragma unroll
        for (int ks = 0; ks < 4; ++ks)
            w1f[mt][ks] = *(const bf16x8*)(w1bf + (mt * 16 + e) * 128 + ks * 32 + c * 8);

    bf16x8 w2f[2][2];
    #pragma unroll
    for (int mt2 = 0; mt2 < 2; ++mt2)
        #pragma unroll
        for (int ks2 = 0; ks2 < 2; ++ks2)
            w2f[mt2][ks2] = *(const bf16x8*)(w2bf + (mt2 * 16 + e) * 64 + ks2 * 32 + c * 8);

    f32x4 bias1[4];
    #pragma unroll
    for (int mt = 0; mt < 4; ++mt) bias1[mt] = *(const f32x4*)(b1 + mt * 16 + c * 4);
    f32x4 bias2[2];
    #pragma unroll
    for (int mt2 = 0; mt2 < 2; ++mt2) bias2[mt2] = *(const f32x4*)(b2 + mt2 * 16 + c * 4);
    f32x4 w3v[2];
    #pragma unroll
    for (int mt2 = 0; mt2 < 2; ++mt2) w3v[mt2] = *(const f32x4*)(W3 + mt2 * 16 + c * 4);
    const float b3v = b3[0];

    const int nw = (gridDim.x * blockDim.x) >> 6;
    const int wv = (blockIdx.x * blockDim.x + tid) >> 6;
    const int NT = NE / 16;   // 50000 tiles

    for (int tile = wv; tile < NT; tile += nw) {
        int p0 = tile * 16 + e;
        int ni = ep[p0];
        int nj = ep[NE + p0];
        const ushort_t* zi = zbf + (size_t)ni * DOUT;
        const ushort_t* zj = zbf + (size_t)nj * DOUT;

        bf16x8 bfr[4];
        bfr[0] = *(const bf16x8*)(zi + c * 8);
        bfr[1] = *(const bf16x8*)(zi + 32 + c * 8);
        bfr[2] = *(const bf16x8*)(zj + c * 8);
        bfr[3] = *(const bf16x8*)(zj + 32 + c * 8);

        f32x4 acc[4];
        #pragma unroll
        for (int mt = 0; mt < 4; ++mt) acc[mt] = bias1[mt];

        #pragma unroll
        for (int ks = 0; ks < 4; ++ks)
            #pragma unroll
            for (int mt = 0; mt < 4; ++mt)
                acc[mt] = __builtin_amdgcn_mfma_f32_16x16x32_bf16(w1f[mt][ks], bfr[ks], acc[mt], 0, 0, 0);

        // relu -> bf16 -> LDS (neuron index n = mt*16 + c*4 + r, row = e)
        #pragma unroll
        for (int mt = 0; mt < 4; ++mt) {
            uint_t lo = (uint_t)f2bf(fmaxf(acc[mt][0], 0.f)) | ((uint_t)f2bf(fmaxf(acc[mt][1], 0.f)) << 16);
            uint_t hi = (uint_t)f2bf(fmaxf(acc[mt][2], 0.f)) | ((uint_t)f2bf(fmaxf(acc[mt][3], 0.f)) << 16);
            uint_t off = (uint_t)(e * 128 + mt * 32 + c * 8) ^ swz;
            *(uint2*)((char*)lds + off) = make_uint2(lo, hi);
        }

        bf16x8 b2f[2];
        #pragma unroll
        for (int ks2 = 0; ks2 < 2; ++ks2) {
            uint_t off = (uint_t)(e * 128 + ks2 * 64 + c * 16) ^ swz;
            b2f[ks2] = *(const bf16x8*)((const char*)lds + off);
        }

        f32x4 a2[2];
        #pragma unroll
        for (int mt2 = 0; mt2 < 2; ++mt2) a2[mt2] = bias2[mt2];
        #pragma unroll
        for (int ks2 = 0; ks2 < 2; ++ks2)
            #pragma unroll
            for (int mt2 = 0; mt2 < 2; ++mt2)
                a2[mt2] = __builtin_amdgcn_mfma_f32_16x16x32_bf16(w2f[mt2][ks2], b2f[ks2], a2[mt2], 0, 0, 0);

        float t3 = b3v;
        #pragma unroll
        for (int mt2 = 0; mt2 < 2; ++mt2)
            #pragma unroll
            for (int r = 0; r < 4; ++r)
                t3 += fmaxf(a2[mt2][r], 0.f) * w3v[mt2][r];

        t3 += __shfl_xor(t3, 16);
        t3 += __shfl_xor(t3, 32);

        if (lane < 16) out[p0] = 1.f / (1.f + expf(-t3));
    }
}

// ---------------------------------------------------------------------------
extern "C" void kernel_launch(void* const* d_in, const int* in_sizes, int n_in,
                              void* d_out, int out_size, void* d_ws, size_t ws_size,
                              hipStream_t stream)
{
    const float* x     = (const float*)d_in[0];
    const int*   ei    = (const int*)d_in[1];
    const int*   ep    = (const int*)d_in[2];
    const float* c1_Wl = (const float*)d_in[3];
    const float* c1_bl = (const float*)d_in[4];
    const float* c1_Wr = (const float*)d_in[5];
    const float* bn_g  = (const float*)d_in[6];
    const float* bn_b  = (const float*)d_in[7];
    const float* bn_m  = (const float*)d_in[8];
    const float* bn_v  = (const float*)d_in[9];
    const float* c2_Wl = (const float*)d_in[10];
    const float* c2_bl = (const float*)d_in[11];
    const float* c2_Wr = (const float*)d_in[12];
    const float* e_W1  = (const float*)d_in[13];
    const float* e_b1  = (const float*)d_in[14];
    const float* e_W2  = (const float*)d_in[15];
    const float* e_b2  = (const float*)d_in[16];
    const float* e_W3  = (const float*)d_in[17];
    const float* e_b3  = (const float*)d_in[18];
    float* out = (float*)d_out;

    // ws layout: mean f32[6.4M] | h f32[6.4M] | zbf bf16[3.2M] | w1bf[8192] | w2bf[2048] | CSR ints
    float*    mean   = (float*)d_ws;
    float*    h      = mean + (size_t)NN * DIN;
    ushort_t* zbf    = (ushort_t*)(h + (size_t)NN * DHID);
    ushort_t* w1bf   = zbf + (size_t)NN * DOUT;
    ushort_t* w2bf   = w1bf + 64 * 128;
    int*      deg    = (int*)(w2bf + 32 * 64);
    int*      cursor = deg + 50048;
    int*      rowptr = cursor + 50048;
    int*      csr_src= rowptr + 50052;

    hipMemsetAsync(deg, 0, (size_t)(50048 * 2) * sizeof(int), stream);

    k_deg <<<3125, 256, 0, stream>>>(ei, deg);
    k_scan<<<1, 256, 0, stream>>>(deg, rowptr);
    k_fill<<<3125, 256, 0, stream>>>(ei, rowptr, cursor, csr_src);
    k_prep<<<1, 256, 0, stream>>>(e_W1, e_W2, w1bf, w2bf);

    k_gather_mean<<<12500, 256, 0, stream>>>(x, rowptr, csr_src, mean);
    k_conv1<<<782, 256, 0, stream>>>(x, mean, c1_Wl, c1_bl, c1_Wr,
                                     bn_g, bn_b, bn_m, bn_v, h);

    k_gather_mean<<<12500, 256, 0, stream>>>(h, rowptr, csr_src, mean);
    k_conv2<<<391, 256, 0, stream>>>(h, mean, c2_Wl, c2_bl, c2_Wr, zbf);

    k_edge<<<1024, 256, 0, stream>>>(zbf, ep, w1bf, e_b1, w2bf, e_b2,
                                     e_W3, e_b3, out);
}

// Round 5
// 422.139 us; speedup vs baseline: 8.5318x; 1.8237x over previous
//
#include <hip/hip_runtime.h>
#include <math.h>

#define NN 50000
#define NE 800000
#define DIN 128
#define DHID 128
#define DOUT 64
#define BN_EPS 1e-5f

typedef __attribute__((ext_vector_type(8))) short bf16x8;
typedef __attribute__((ext_vector_type(8))) _Float16 f16x8;
typedef __attribute__((ext_vector_type(4))) _Float16 f16x4;
typedef __attribute__((ext_vector_type(2))) _Float16 f16x2;
typedef __attribute__((ext_vector_type(4))) float f32x4;
typedef unsigned short ushort_t;
typedef unsigned int uint_t;

__device__ __forceinline__ ushort_t f2bf(float f) {
    uint_t u = __float_as_uint(f);
    uint_t r = (u + 0x7FFFu + ((u >> 16) & 1u)) >> 16;   // round-to-nearest-even
    return (ushort_t)r;
}

// ---------------------------------------------------------------------------
// CSR build: histogram of dst degrees.
__global__ __launch_bounds__(256) void k_deg(const int* __restrict__ ei, int* __restrict__ deg)
{
    int e = blockIdx.x * blockDim.x + threadIdx.x;
    if (e >= NE) return;
    atomicAdd(deg + ei[NE + e], 1);
}

// Exclusive prefix sum over deg[NN] -> rowptr[NN+1]. Single block, 256 threads.
__global__ __launch_bounds__(256) void k_scan(const int* __restrict__ deg, int* __restrict__ rowptr)
{
    __shared__ int part[256];
    const int CH = (NN + 255) / 256;
    int t = threadIdx.x;
    int beg = t * CH;
    int end = beg + CH < NN ? beg + CH : NN;
    int s = 0;
    for (int i = beg; i < end; ++i) s += deg[i];
    part[t] = s;
    __syncthreads();
    if (t == 0) {
        int acc = 0;
        for (int i = 0; i < 256; ++i) { int v = part[i]; part[i] = acc; acc += v; }
    }
    __syncthreads();
    int run = part[t];
    for (int i = beg; i < end; ++i) { rowptr[i] = run; run += deg[i]; }
    if (t == 255) rowptr[NN] = NE;
}

// Fill CSR column (src) array.
__global__ __launch_bounds__(256) void k_fill(
    const int* __restrict__ ei, const int* __restrict__ rowptr,
    int* __restrict__ cursor, int* __restrict__ csr_src)
{
    int e = blockIdx.x * blockDim.x + threadIdx.x;
    if (e >= NE) return;
    int dst = ei[NE + e];
    int slot = atomicAdd(cursor + dst, 1);
    csr_src[rowptr[dst] + slot] = ei[e];
}

// ---------------------------------------------------------------------------
// Weight prep: conv weights -> fp16 concat [out][mean_k | root_k]; edge weights
// -> bf16; BN folded to scale/shift.
__global__ __launch_bounds__(256) void k_prep(
    const float* __restrict__ c1_Wl, const float* __restrict__ c1_Wr,
    const float* __restrict__ c2_Wl, const float* __restrict__ c2_Wr,
    const float* __restrict__ gam, const float* __restrict__ bet,
    const float* __restrict__ bmean, const float* __restrict__ bvar,
    const float* __restrict__ eW1, const float* __restrict__ eW2,
    _Float16* __restrict__ w1cat, _Float16* __restrict__ w2cat,
    ushort_t* __restrict__ w1bf, ushort_t* __restrict__ w2bf,
    float* __restrict__ bnsc, float* __restrict__ bnsh)
{
    int t = threadIdx.x;
    for (int i = t; i < 128 * 128; i += 256) {
        int row = i >> 7, k = i & 127;
        w1cat[row * 256 + k]       = (_Float16)c1_Wl[i];
        w1cat[row * 256 + 128 + k] = (_Float16)c1_Wr[i];
    }
    for (int i = t; i < 64 * 128; i += 256) {
        int row = i >> 7, k = i & 127;
        w2cat[row * 256 + k]       = (_Float16)c2_Wl[i];
        w2cat[row * 256 + 128 + k] = (_Float16)c2_Wr[i];
    }
    for (int i = t; i < 64 * 128; i += 256) w1bf[i] = f2bf(eW1[i]);
    for (int i = t; i < 32 * 64; i += 256)  w2bf[i] = f2bf(eW2[i]);
    for (int i = t; i < 128; i += 256) {
        float s = gam[i] * rsqrtf(bvar[i] + BN_EPS);
        bnsc[i] = s;
        bnsh[i] = bet[i] - bmean[i] * s;
    }
}

// Cast x (f32) -> fp16, 8 elems/thread.
__global__ __launch_bounds__(256) void k_xcast(const float* __restrict__ x, _Float16* __restrict__ xh)
{
    int i = blockIdx.x * blockDim.x + threadIdx.x;
    if (i >= NN * DIN / 8) return;
    const float4* src = (const float4*)x + (size_t)i * 2;
    float4 a = src[0], b = src[1];
    f16x8 o;
    o[0] = (_Float16)a.x; o[1] = (_Float16)a.y; o[2] = (_Float16)a.z; o[3] = (_Float16)a.w;
    o[4] = (_Float16)b.x; o[5] = (_Float16)b.y; o[6] = (_Float16)b.z; o[7] = (_Float16)b.w;
    *(f16x8*)(xh + (size_t)i * 8) = o;
}

// ---------------------------------------------------------------------------
// Gather-mean over CSR, fp16 in/out, f32 accumulate. One wave/node, lane = 2 feats.
__global__ __launch_bounds__(256) void k_gather_mean_h(
    const _Float16* __restrict__ feat, const int* __restrict__ rowptr,
    const int* __restrict__ csr_src, _Float16* __restrict__ mean)
{
    int wv = (blockIdx.x * blockDim.x + threadIdx.x) >> 6;
    int lane = threadIdx.x & 63;
    if (wv >= NN) return;
    int beg = rowptr[wv], end = rowptr[wv + 1];

    float2 a0 = {0.f, 0.f}, a1 = {0.f, 0.f};
    int j = beg;
    for (; j + 1 < end; j += 2) {
        int s0 = csr_src[j];
        int s1 = csr_src[j + 1];
        f16x2 v0 = *(const f16x2*)(feat + (size_t)s0 * 128 + lane * 2);
        f16x2 v1 = *(const f16x2*)(feat + (size_t)s1 * 128 + lane * 2);
        a0.x += (float)v0[0]; a0.y += (float)v0[1];
        a1.x += (float)v1[0]; a1.y += (float)v1[1];
    }
    if (j < end) {
        int s0 = csr_src[j];
        f16x2 v0 = *(const f16x2*)(feat + (size_t)s0 * 128 + lane * 2);
        a0.x += (float)v0[0]; a0.y += (float)v0[1];
    }
    float inv = 1.0f / fmaxf((float)(end - beg), 1.0f);
    f16x2 o;
    o[0] = (_Float16)((a0.x + a1.x) * inv);
    o[1] = (_Float16)((a0.y + a1.y) * inv);
    *(f16x2*)(mean + (size_t)wv * 128 + lane * 2) = o;
}

// ---------------------------------------------------------------------------
// Conv1 via MFMA: h = relu(BN(mean@Wl.T + bl + x@Wr.T)), fp16 in, fp16 out.
// Swapped form D[j][node]: wave = col-chunk (32 cols), 16 nodes/block-tile.
// C/D layout: D-col = lane&15 = node, D-row = (lane>>4)*4+reg = within-tile col.
__global__ __launch_bounds__(256) void k_conv1_mfma(
    const _Float16* __restrict__ xh, const _Float16* __restrict__ meanh,
    const _Float16* __restrict__ w1cat, const float* __restrict__ bl,
    const float* __restrict__ bnsc, const float* __restrict__ bnsh,
    _Float16* __restrict__ hh)
{
    const int tid = threadIdx.x;
    const int lane = tid & 63;
    const int e = lane & 15;
    const int c = lane >> 4;
    const int chunk = tid >> 6;        // 4 waves = 4 col-chunks of 32
    const int tile = blockIdx.x;       // 3125 tiles * 16 nodes = 50000 exact
    const int node = tile * 16 + e;

    // weight fragments, wave-resident: rows j = chunk*32 + nt*16 + e, K=256
    f16x8 wf[2][8];
    #pragma unroll
    for (int nt = 0; nt < 2; ++nt)
        #pragma unroll
        for (int ks = 0; ks < 8; ++ks)
            wf[nt][ks] = *(const f16x8*)(w1cat + (size_t)(chunk * 32 + nt * 16 + e) * 256 + ks * 32 + c * 8);

    f32x4 acc[2];
    #pragma unroll
    for (int nt = 0; nt < 2; ++nt)
        acc[nt] = *(const f32x4*)(bl + chunk * 32 + nt * 16 + c * 4);

    // feature fragments: K 0..127 = mean, 128..255 = x
    f16x8 bf[8];
    #pragma unroll
    for (int ks = 0; ks < 4; ++ks)
        bf[ks] = *(const f16x8*)(meanh + (size_t)node * 128 + ks * 32 + c * 8);
    #pragma unroll
    for (int ks = 4; ks < 8; ++ks)
        bf[ks] = *(const f16x8*)(xh + (size_t)node * 128 + (ks - 4) * 32 + c * 8);

    #pragma unroll
    for (int ks = 0; ks < 8; ++ks)
        #pragma unroll
        for (int nt = 0; nt < 2; ++nt)
            acc[nt] = __builtin_amdgcn_mfma_f32_16x16x32_f16(wf[nt][ks], bf[ks], acc[nt], 0, 0, 0);

    #pragma unroll
    for (int nt = 0; nt < 2; ++nt) {
        int j0 = chunk * 32 + nt * 16 + c * 4;
        f32x4 sc = *(const f32x4*)(bnsc + j0);
        f32x4 sh = *(const f32x4*)(bnsh + j0);
        f16x4 o;
        #pragma unroll
        for (int r = 0; r < 4; ++r)
            o[r] = (_Float16)fmaxf(acc[nt][r] * sc[r] + sh[r], 0.f);
        *(f16x4*)(hh + (size_t)node * 128 + j0) = o;
    }
}

// Conv2 via MFMA: z = mean2@Wl.T + bl + h@Wr.T -> bf16. Wave = 16-col chunk.
__global__ __launch_bounds__(256) void k_conv2_mfma(
    const _Float16* __restrict__ hh, const _Float16* __restrict__ meanh,
    const _Float16* __restrict__ w2cat, const float* __restrict__ bl,
    ushort_t* __restrict__ zbf)
{
    const int tid = threadIdx.x;
    const int lane = tid & 63;
    const int e = lane & 15;
    const int c = lane >> 4;
    const int chunk = tid >> 6;        // 4 waves = 4 col-chunks of 16
    const int tile = blockIdx.x;
    const int node = tile * 16 + e;

    f16x8 wf[8];
    #pragma unroll
    for (int ks = 0; ks < 8; ++ks)
        wf[ks] = *(const f16x8*)(w2cat + (size_t)(chunk * 16 + e) * 256 + ks * 32 + c * 8);

    f32x4 acc = *(const f32x4*)(bl + chunk * 16 + c * 4);

    f16x8 bf[8];
    #pragma unroll
    for (int ks = 0; ks < 4; ++ks)
        bf[ks] = *(const f16x8*)(meanh + (size_t)node * 128 + ks * 32 + c * 8);
    #pragma unroll
    for (int ks = 4; ks < 8; ++ks)
        bf[ks] = *(const f16x8*)(hh + (size_t)node * 128 + (ks - 4) * 32 + c * 8);

    #pragma unroll
    for (int ks = 0; ks < 8; ++ks)
        acc = __builtin_amdgcn_mfma_f32_16x16x32_f16(wf[ks], bf[ks], acc, 0, 0, 0);

    int j0 = chunk * 16 + c * 4;
    uint2 pk;
    pk.x = (uint_t)f2bf(acc[0]) | ((uint_t)f2bf(acc[1]) << 16);
    pk.y = (uint_t)f2bf(acc[2]) | ((uint_t)f2bf(acc[3]) << 16);
    *(uint2*)(zbf + (size_t)node * 64 + j0) = pk;
}

// ---------------------------------------------------------------------------
// Edge head via MFMA, 16 edges per wave-tile (unchanged from round 4).
__global__ __launch_bounds__(256, 2) void k_edge(
    const ushort_t* __restrict__ zbf, const int* __restrict__ ep,
    const ushort_t* __restrict__ w1bf, const float* __restrict__ b1,
    const ushort_t* __restrict__ w2bf, const float* __restrict__ b2,
    const float* __restrict__ W3, const float* __restrict__ b3,
    float* __restrict__ out)
{
    __shared__ ushort_t a1lds[4][16 * 64];   // 2 KB per wave
    const int tid  = threadIdx.x;
    const int lane = tid & 63;
    const int e    = lane & 15;
    const int c    = lane >> 4;
    ushort_t* lds  = &a1lds[tid >> 6][0];
    const uint_t swz = (uint_t)((e & 7) << 4);

    bf16x8 w1f[4][4];
    #pragma unroll
    for (int mt = 0; mt < 4; ++mt)
        #pragma unroll
        for (int ks = 0; ks < 4; ++ks)
            w1f[mt][ks] = *(const bf16x8*)(w1bf + (mt * 16 + e) * 128 + ks * 32 + c * 8);

    bf16x8 w2f[2][2];
    #pragma unroll
    for (int mt2 = 0; mt2 < 2; ++mt2)
        #pragma unroll
        for (int ks2 = 0; ks2 < 2; ++ks2)
            w2f[mt2][ks2] = *(const bf16x8*)(w2bf + (mt2 * 16 + e) * 64 + ks2 * 32 + c * 8);

    f32x4 bias1[4];
    #pragma unroll
    for (int mt = 0; mt < 4; ++mt) bias1[mt] = *(const f32x4*)(b1 + mt * 16 + c * 4);
    f32x4 bias2[2];
    #pragma unroll
    for (int mt2 = 0; mt2 < 2; ++mt2) bias2[mt2] = *(const f32x4*)(b2 + mt2 * 16 + c * 4);
    f32x4 w3v[2];
    #pragma unroll
    for (int mt2 = 0; mt2 < 2; ++mt2) w3v[mt2] = *(const f32x4*)(W3 + mt2 * 16 + c * 4);
    const float b3v = b3[0];

    const int nw = (gridDim.x * blockDim.x) >> 6;
    const int wv = (blockIdx.x * blockDim.x + tid) >> 6;
    const int NT = NE / 16;

    for (int tile = wv; tile < NT; tile += nw) {
        int p0 = tile * 16 + e;
        int ni = ep[p0];
        int nj = ep[NE + p0];
        const ushort_t* zi = zbf + (size_t)ni * DOUT;
        const ushort_t* zj = zbf + (size_t)nj * DOUT;

        bf16x8 bfr[4];
        bfr[0] = *(const bf16x8*)(zi + c * 8);
        bfr[1] = *(const bf16x8*)(zi + 32 + c * 8);
        bfr[2] = *(const bf16x8*)(zj + c * 8);
        bfr[3] = *(const bf16x8*)(zj + 32 + c * 8);

        f32x4 acc[4];
        #pragma unroll
        for (int mt = 0; mt < 4; ++mt) acc[mt] = bias1[mt];

        #pragma unroll
        for (int ks = 0; ks < 4; ++ks)
            #pragma unroll
            for (int mt = 0; mt < 4; ++mt)
                acc[mt] = __builtin_amdgcn_mfma_f32_16x16x32_bf16(w1f[mt][ks], bfr[ks], acc[mt], 0, 0, 0);

        #pragma unroll
        for (int mt = 0; mt < 4; ++mt) {
            uint_t lo = (uint_t)f2bf(fmaxf(acc[mt][0], 0.f)) | ((uint_t)f2bf(fmaxf(acc[mt][1], 0.f)) << 16);
            uint_t hi = (uint_t)f2bf(fmaxf(acc[mt][2], 0.f)) | ((uint_t)f2bf(fmaxf(acc[mt][3], 0.f)) << 16);
            uint_t off = (uint_t)(e * 128 + mt * 32 + c * 8) ^ swz;
            *(uint2*)((char*)lds + off) = make_uint2(lo, hi);
        }

        bf16x8 b2f[2];
        #pragma unroll
        for (int ks2 = 0; ks2 < 2; ++ks2) {
            uint_t off = (uint_t)(e * 128 + ks2 * 64 + c * 16) ^ swz;
            b2f[ks2] = *(const bf16x8*)((const char*)lds + off);
        }

        f32x4 a2[2];
        #pragma unroll
        for (int mt2 = 0; mt2 < 2; ++mt2) a2[mt2] = bias2[mt2];
        #pragma unroll
        for (int ks2 = 0; ks2 < 2; ++ks2)
            #pragma unroll
            for (int mt2 = 0; mt2 < 2; ++mt2)
                a2[mt2] = __builtin_amdgcn_mfma_f32_16x16x32_bf16(w2f[mt2][ks2], b2f[ks2], a2[mt2], 0, 0, 0);

        float t3 = b3v;
        #pragma unroll
        for (int mt2 = 0; mt2 < 2; ++mt2)
            #pragma unroll
            for (int r = 0; r < 4; ++r)
                t3 += fmaxf(a2[mt2][r], 0.f) * w3v[mt2][r];

        t3 += __shfl_xor(t3, 16);
        t3 += __shfl_xor(t3, 32);

        if (lane < 16) out[p0] = 1.f / (1.f + expf(-t3));
    }
}

// ---------------------------------------------------------------------------
extern "C" void kernel_launch(void* const* d_in, const int* in_sizes, int n_in,
                              void* d_out, int out_size, void* d_ws, size_t ws_size,
                              hipStream_t stream)
{
    const float* x     = (const float*)d_in[0];
    const int*   ei    = (const int*)d_in[1];
    const int*   ep    = (const int*)d_in[2];
    const float* c1_Wl = (const float*)d_in[3];
    const float* c1_bl = (const float*)d_in[4];
    const float* c1_Wr = (const float*)d_in[5];
    const float* bn_g  = (const float*)d_in[6];
    const float* bn_b  = (const float*)d_in[7];
    const float* bn_m  = (const float*)d_in[8];
    const float* bn_v  = (const float*)d_in[9];
    const float* c2_Wl = (const float*)d_in[10];
    const float* c2_bl = (const float*)d_in[11];
    const float* c2_Wr = (const float*)d_in[12];
    const float* e_W1  = (const float*)d_in[13];
    const float* e_b1  = (const float*)d_in[14];
    const float* e_W2  = (const float*)d_in[15];
    const float* e_b2  = (const float*)d_in[16];
    const float* e_W3  = (const float*)d_in[17];
    const float* e_b3  = (const float*)d_in[18];
    float* out = (float*)d_out;

    // ws layout (halfs): xh[6.4M] | meanh[6.4M] | hh[6.4M] | zbf[3.2M]
    //                  | w1cat[32768] | w2cat[16384] | w1bf[8192] | w2bf[2048]
    //                  | bnsc/bnsh f32[256] | CSR ints
    _Float16* xh    = (_Float16*)d_ws;
    _Float16* meanh = xh + (size_t)NN * DIN;
    _Float16* hh    = meanh + (size_t)NN * DIN;
    ushort_t* zbf   = (ushort_t*)(hh + (size_t)NN * DHID);
    _Float16* w1cat = (_Float16*)(zbf + (size_t)NN * DOUT);
    _Float16* w2cat = w1cat + 128 * 256;
    ushort_t* w1bf  = (ushort_t*)(w2cat + 64 * 256);
    ushort_t* w2bf  = w1bf + 64 * 128;
    float*    bnsc  = (float*)(w2bf + 32 * 64);
    float*    bnsh  = bnsc + 128;
    int*      deg     = (int*)(bnsh + 128);
    int*      cursor  = deg + 50048;
    int*      rowptr  = cursor + 50048;
    int*      csr_src = rowptr + 50052;

    hipMemsetAsync(deg, 0, (size_t)(50048 * 2) * sizeof(int), stream);

    k_deg <<<3125, 256, 0, stream>>>(ei, deg);
    k_scan<<<1, 256, 0, stream>>>(deg, rowptr);
    k_fill<<<3125, 256, 0, stream>>>(ei, rowptr, cursor, csr_src);
    k_prep<<<1, 256, 0, stream>>>(c1_Wl, c1_Wr, c2_Wl, c2_Wr,
                                  bn_g, bn_b, bn_m, bn_v, e_W1, e_W2,
                                  w1cat, w2cat, w1bf, w2bf, bnsc, bnsh);
    k_xcast<<<3125, 256, 0, stream>>>(x, xh);

    k_gather_mean_h<<<12500, 256, 0, stream>>>(xh, rowptr, csr_src, meanh);
    k_conv1_mfma<<<3125, 256, 0, stream>>>(xh, meanh, w1cat, c1_bl, bnsc, bnsh, hh);

    k_gather_mean_h<<<12500, 256, 0, stream>>>(hh, rowptr, csr_src, meanh);
    k_conv2_mfma<<<3125, 256, 0, stream>>>(hh, meanh, w2cat, c2_bl, zbf);

    k_edge<<<1024, 256, 0, stream>>>(zbf, ep, w1bf, e_b1, w2bf, e_b2,
                                     e_W3, e_b3, out);
}

// Round 6
// 385.862 us; speedup vs baseline: 9.3340x; 1.0940x over previous
//
#include <hip/hip_runtime.h>
#include <math.h>

#define NN 50000
#define NE 800000
#define DIN 128
#define DHID 128
#define DOUT 64
#define BN_EPS 1e-5f

typedef __attribute__((ext_vector_type(8))) short bf16x8;
typedef __attribute__((ext_vector_type(8))) _Float16 f16x8;
typedef __attribute__((ext_vector_type(4))) _Float16 f16x4;
typedef __attribute__((ext_vector_type(2))) _Float16 f16x2;
typedef __attribute__((ext_vector_type(4))) float f32x4;
typedef unsigned short ushort_t;
typedef unsigned int uint_t;

__device__ __forceinline__ ushort_t f2bf(float f) {
    uint_t u = __float_as_uint(f);
    uint_t r = (u + 0x7FFFu + ((u >> 16) & 1u)) >> 16;   // round-to-nearest-even
    return (ushort_t)r;
}

// ---------------------------------------------------------------------------
// CSR build: histogram of dst degrees.
__global__ __launch_bounds__(256) void k_deg(const int* __restrict__ ei, int* __restrict__ deg)
{
    int e = blockIdx.x * blockDim.x + threadIdx.x;
    if (e >= NE) return;
    atomicAdd(deg + ei[NE + e], 1);
}

// Exclusive prefix sum over deg[NN] -> rowptr[NN+1].
// One 1024-thread block: 49 elems/thread (independent loads), 10-step LDS scan.
__global__ __launch_bounds__(1024) void k_scan(const int* __restrict__ deg, int* __restrict__ rowptr)
{
    __shared__ int s[1024];
    const int CH = (NN + 1023) / 1024;   // 49
    int t = threadIdx.x;
    int beg = t * CH;
    int end = beg + CH < NN ? beg + CH : NN;
    int part = 0;
    for (int i = beg; i < end; ++i) part += deg[i];
    s[t] = part;
    __syncthreads();
    #pragma unroll
    for (int off = 1; off < 1024; off <<= 1) {
        int v = (t >= off) ? s[t - off] : 0;
        __syncthreads();
        s[t] += v;
        __syncthreads();
    }
    int run = (t == 0) ? 0 : s[t - 1];   // exclusive prefix of this thread's chunk
    for (int i = beg; i < end; ++i) { rowptr[i] = run; run += deg[i]; }
    if (t == 1023) rowptr[NN] = NE;
}

// Fill CSR column (src) array.
__global__ __launch_bounds__(256) void k_fill(
    const int* __restrict__ ei, const int* __restrict__ rowptr,
    int* __restrict__ cursor, int* __restrict__ csr_src)
{
    int e = blockIdx.x * blockDim.x + threadIdx.x;
    if (e >= NE) return;
    int dst = ei[NE + e];
    int slot = atomicAdd(cursor + dst, 1);
    csr_src[rowptr[dst] + slot] = ei[e];
}

// ---------------------------------------------------------------------------
// Weight prep: conv weights -> fp16 concat [out][mean_k | root_k]; edge weights
// -> bf16; BN folded to scale/shift.
__global__ __launch_bounds__(256) void k_prep(
    const float* __restrict__ c1_Wl, const float* __restrict__ c1_Wr,
    const float* __restrict__ c2_Wl, const float* __restrict__ c2_Wr,
    const float* __restrict__ gam, const float* __restrict__ bet,
    const float* __restrict__ bmean, const float* __restrict__ bvar,
    const float* __restrict__ eW1, const float* __restrict__ eW2,
    _Float16* __restrict__ w1cat, _Float16* __restrict__ w2cat,
    ushort_t* __restrict__ w1bf, ushort_t* __restrict__ w2bf,
    float* __restrict__ bnsc, float* __restrict__ bnsh)
{
    int t = threadIdx.x;
    for (int i = t; i < 128 * 128; i += 256) {
        int row = i >> 7, k = i & 127;
        w1cat[row * 256 + k]       = (_Float16)c1_Wl[i];
        w1cat[row * 256 + 128 + k] = (_Float16)c1_Wr[i];
    }
    for (int i = t; i < 64 * 128; i += 256) {
        int row = i >> 7, k = i & 127;
        w2cat[row * 256 + k]       = (_Float16)c2_Wl[i];
        w2cat[row * 256 + 128 + k] = (_Float16)c2_Wr[i];
    }
    for (int i = t; i < 64 * 128; i += 256) w1bf[i] = f2bf(eW1[i]);
    for (int i = t; i < 32 * 64; i += 256)  w2bf[i] = f2bf(eW2[i]);
    for (int i = t; i < 128; i += 256) {
        float s = gam[i] * rsqrtf(bvar[i] + BN_EPS);
        bnsc[i] = s;
        bnsh[i] = bet[i] - bmean[i] * s;
    }
}

// Cast x (f32) -> fp16, 8 elems/thread.
__global__ __launch_bounds__(256) void k_xcast(const float* __restrict__ x, _Float16* __restrict__ xh)
{
    int i = blockIdx.x * blockDim.x + threadIdx.x;
    if (i >= NN * DIN / 8) return;
    const float4* src = (const float4*)x + (size_t)i * 2;
    float4 a = src[0], b = src[1];
    f16x8 o;
    o[0] = (_Float16)a.x; o[1] = (_Float16)a.y; o[2] = (_Float16)a.z; o[3] = (_Float16)a.w;
    o[4] = (_Float16)b.x; o[5] = (_Float16)b.y; o[6] = (_Float16)b.z; o[7] = (_Float16)b.w;
    *(f16x8*)(xh + (size_t)i * 8) = o;
}

// ---------------------------------------------------------------------------
// Gather-mean over CSR, fp16 in/out, f32 accumulate, 4-way unrolled for MLP.
__global__ __launch_bounds__(256) void k_gather_mean_h(
    const _Float16* __restrict__ feat, const int* __restrict__ rowptr,
    const int* __restrict__ csr_src, _Float16* __restrict__ mean)
{
    int wv = (blockIdx.x * blockDim.x + threadIdx.x) >> 6;
    int lane = threadIdx.x & 63;
    if (wv >= NN) return;
    int beg = rowptr[wv], end = rowptr[wv + 1];

    float2 a0 = {0.f, 0.f}, a1 = {0.f, 0.f}, a2 = {0.f, 0.f}, a3 = {0.f, 0.f};
    int j = beg;
    for (; j + 3 < end; j += 4) {
        int s0 = csr_src[j];
        int s1 = csr_src[j + 1];
        int s2 = csr_src[j + 2];
        int s3 = csr_src[j + 3];
        f16x2 v0 = *(const f16x2*)(feat + (size_t)s0 * 128 + lane * 2);
        f16x2 v1 = *(const f16x2*)(feat + (size_t)s1 * 128 + lane * 2);
        f16x2 v2 = *(const f16x2*)(feat + (size_t)s2 * 128 + lane * 2);
        f16x2 v3 = *(const f16x2*)(feat + (size_t)s3 * 128 + lane * 2);
        a0.x += (float)v0[0]; a0.y += (float)v0[1];
        a1.x += (float)v1[0]; a1.y += (float)v1[1];
        a2.x += (float)v2[0]; a2.y += (float)v2[1];
        a3.x += (float)v3[0]; a3.y += (float)v3[1];
    }
    for (; j < end; ++j) {
        int s0 = csr_src[j];
        f16x2 v0 = *(const f16x2*)(feat + (size_t)s0 * 128 + lane * 2);
        a0.x += (float)v0[0]; a0.y += (float)v0[1];
    }
    float inv = 1.0f / fmaxf((float)(end - beg), 1.0f);
    f16x2 o;
    o[0] = (_Float16)((a0.x + a1.x + a2.x + a3.x) * inv);
    o[1] = (_Float16)((a0.y + a1.y + a2.y + a3.y) * inv);
    *(f16x2*)(mean + (size_t)wv * 128 + lane * 2) = o;
}

// ---------------------------------------------------------------------------
// Conv1 via MFMA: h = relu(BN(mean@Wl.T + bl + x@Wr.T)), fp16 in, fp16 out.
__global__ __launch_bounds__(256) void k_conv1_mfma(
    const _Float16* __restrict__ xh, const _Float16* __restrict__ meanh,
    const _Float16* __restrict__ w1cat, const float* __restrict__ bl,
    const float* __restrict__ bnsc, const float* __restrict__ bnsh,
    _Float16* __restrict__ hh)
{
    const int tid = threadIdx.x;
    const int lane = tid & 63;
    const int e = lane & 15;
    const int c = lane >> 4;
    const int chunk = tid >> 6;        // 4 waves = 4 col-chunks of 32
    const int tile = blockIdx.x;       // 3125 tiles * 16 nodes = 50000 exact
    const int node = tile * 16 + e;

    f16x8 wf[2][8];
    #pragma unroll
    for (int nt = 0; nt < 2; ++nt)
        #pragma unroll
        for (int ks = 0; ks < 8; ++ks)
            wf[nt][ks] = *(const f16x8*)(w1cat + (size_t)(chunk * 32 + nt * 16 + e) * 256 + ks * 32 + c * 8);

    f32x4 acc[2];
    #pragma unroll
    for (int nt = 0; nt < 2; ++nt)
        acc[nt] = *(const f32x4*)(bl + chunk * 32 + nt * 16 + c * 4);

    f16x8 bf[8];
    #pragma unroll
    for (int ks = 0; ks < 4; ++ks)
        bf[ks] = *(const f16x8*)(meanh + (size_t)node * 128 + ks * 32 + c * 8);
    #pragma unroll
    for (int ks = 4; ks < 8; ++ks)
        bf[ks] = *(const f16x8*)(xh + (size_t)node * 128 + (ks - 4) * 32 + c * 8);

    #pragma unroll
    for (int ks = 0; ks < 8; ++ks)
        #pragma unroll
        for (int nt = 0; nt < 2; ++nt)
            acc[nt] = __builtin_amdgcn_mfma_f32_16x16x32_f16(wf[nt][ks], bf[ks], acc[nt], 0, 0, 0);

    #pragma unroll
    for (int nt = 0; nt < 2; ++nt) {
        int j0 = chunk * 32 + nt * 16 + c * 4;
        f32x4 sc = *(const f32x4*)(bnsc + j0);
        f32x4 sh = *(const f32x4*)(bnsh + j0);
        f16x4 o;
        #pragma unroll
        for (int r = 0; r < 4; ++r)
            o[r] = (_Float16)fmaxf(acc[nt][r] * sc[r] + sh[r], 0.f);
        *(f16x4*)(hh + (size_t)node * 128 + j0) = o;
    }
}

// Conv2 via MFMA: z = mean2@Wl.T + bl + h@Wr.T -> bf16.
__global__ __launch_bounds__(256) void k_conv2_mfma(
    const _Float16* __restrict__ hh, const _Float16* __restrict__ meanh,
    const _Float16* __restrict__ w2cat, const float* __restrict__ bl,
    ushort_t* __restrict__ zbf)
{
    const int tid = threadIdx.x;
    const int lane = tid & 63;
    const int e = lane & 15;
    const int c = lane >> 4;
    const int chunk = tid >> 6;        // 4 waves = 4 col-chunks of 16
    const int tile = blockIdx.x;
    const int node = tile * 16 + e;

    f16x8 wf[8];
    #pragma unroll
    for (int ks = 0; ks < 8; ++ks)
        wf[ks] = *(const f16x8*)(w2cat + (size_t)(chunk * 16 + e) * 256 + ks * 32 + c * 8);

    f32x4 acc = *(const f32x4*)(bl + chunk * 16 + c * 4);

    f16x8 bf[8];
    #pragma unroll
    for (int ks = 0; ks < 4; ++ks)
        bf[ks] = *(const f16x8*)(meanh + (size_t)node * 128 + ks * 32 + c * 8);
    #pragma unroll
    for (int ks = 4; ks < 8; ++ks)
        bf[ks] = *(const f16x8*)(hh + (size_t)node * 128 + (ks - 4) * 32 + c * 8);

    #pragma unroll
    for (int ks = 0; ks < 8; ++ks)
        acc = __builtin_amdgcn_mfma_f32_16x16x32_f16(wf[ks], bf[ks], acc, 0, 0, 0);

    int j0 = chunk * 16 + c * 4;
    uint2 pk;
    pk.x = (uint_t)f2bf(acc[0]) | ((uint_t)f2bf(acc[1]) << 16);
    pk.y = (uint_t)f2bf(acc[2]) | ((uint_t)f2bf(acc[3]) << 16);
    *(uint2*)(zbf + (size_t)node * 64 + j0) = pk;
}

// ---------------------------------------------------------------------------
// Edge head via MFMA, 16 edges per wave-tile.
__global__ __launch_bounds__(256, 2) void k_edge(
    const ushort_t* __restrict__ zbf, const int* __restrict__ ep,
    const ushort_t* __restrict__ w1bf, const float* __restrict__ b1,
    const ushort_t* __restrict__ w2bf, const float* __restrict__ b2,
    const float* __restrict__ W3, const float* __restrict__ b3,
    float* __restrict__ out)
{
    __shared__ ushort_t a1lds[4][16 * 64];   // 2 KB per wave
    const int tid  = threadIdx.x;
    const int lane = tid & 63;
    const int e    = lane & 15;
    const int c    = lane >> 4;
    ushort_t* lds  = &a1lds[tid >> 6][0];
    const uint_t swz = (uint_t)((e & 7) << 4);

    bf16x8 w1f[4][4];
    #pragma unroll
    for (int mt = 0; mt < 4; ++mt)
        #pragma unroll
        for (int ks = 0; ks < 4; ++ks)
            w1f[mt][ks] = *(const bf16x8*)(w1bf + (mt * 16 + e) * 128 + ks * 32 + c * 8);

    bf16x8 w2f[2][2];
    #pragma unroll
    for (int mt2 = 0; mt2 < 2; ++mt2)
        #pragma unroll
        for (int ks2 = 0; ks2 < 2; ++ks2)
            w2f[mt2][ks2] = *(const bf16x8*)(w2bf + (mt2 * 16 + e) * 64 + ks2 * 32 + c * 8);

    f32x4 bias1[4];
    #pragma unroll
    for (int mt = 0; mt < 4; ++mt) bias1[mt] = *(const f32x4*)(b1 + mt * 16 + c * 4);
    f32x4 bias2[2];
    #pragma unroll
    for (int mt2 = 0; mt2 < 2; ++mt2) bias2[mt2] = *(const f32x4*)(b2 + mt2 * 16 + c * 4);
    f32x4 w3v[2];
    #pragma unroll
    for (int mt2 = 0; mt2 < 2; ++mt2) w3v[mt2] = *(const f32x4*)(W3 + mt2 * 16 + c * 4);
    const float b3v = b3[0];

    const int nw = (gridDim.x * blockDim.x) >> 6;
    const int wv = (blockIdx.x * blockDim.x + tid) >> 6;
    const int NT = NE / 16;

    for (int tile = wv; tile < NT; tile += nw) {
        int p0 = tile * 16 + e;
        int ni = ep[p0];
        int nj = ep[NE + p0];
        const ushort_t* zi = zbf + (size_t)ni * DOUT;
        const ushort_t* zj = zbf + (size_t)nj * DOUT;

        bf16x8 bfr[4];
        bfr[0] = *(const bf16x8*)(zi + c * 8);
        bfr[1] = *(const bf16x8*)(zi + 32 + c * 8);
        bfr[2] = *(const bf16x8*)(zj + c * 8);
        bfr[3] = *(const bf16x8*)(zj + 32 + c * 8);

        f32x4 acc[4];
        #pragma unroll
        for (int mt = 0; mt < 4; ++mt) acc[mt] = bias1[mt];

        #pragma unroll
        for (int ks = 0; ks < 4; ++ks)
            #pragma unroll
            for (int mt = 0; mt < 4; ++mt)
                acc[mt] = __builtin_amdgcn_mfma_f32_16x16x32_bf16(w1f[mt][ks], bfr[ks], acc[mt], 0, 0, 0);

        #pragma unroll
        for (int mt = 0; mt < 4; ++mt) {
            uint_t lo = (uint_t)f2bf(fmaxf(acc[mt][0], 0.f)) | ((uint_t)f2bf(fmaxf(acc[mt][1], 0.f)) << 16);
            uint_t hi = (uint_t)f2bf(fmaxf(acc[mt][2], 0.f)) | ((uint_t)f2bf(fmaxf(acc[mt][3], 0.f)) << 16);
            uint_t off = (uint_t)(e * 128 + mt * 32 + c * 8) ^ swz;
            *(uint2*)((char*)lds + off) = make_uint2(lo, hi);
        }

        bf16x8 b2f[2];
        #pragma unroll
        for (int ks2 = 0; ks2 < 2; ++ks2) {
            uint_t off = (uint_t)(e * 128 + ks2 * 64 + c * 16) ^ swz;
            b2f[ks2] = *(const bf16x8*)((const char*)lds + off);
        }

        f32x4 a2[2];
        #pragma unroll
        for (int mt2 = 0; mt2 < 2; ++mt2) a2[mt2] = bias2[mt2];
        #pragma unroll
        for (int ks2 = 0; ks2 < 2; ++ks2)
            #pragma unroll
            for (int mt2 = 0; mt2 < 2; ++mt2)
                a2[mt2] = __builtin_amdgcn_mfma_f32_16x16x32_bf16(w2f[mt2][ks2], b2f[ks2], a2[mt2], 0, 0, 0);

        float t3 = b3v;
        #pragma unroll
        for (int mt2 = 0; mt2 < 2; ++mt2)
            #pragma unroll
            for (int r = 0; r < 4; ++r)
                t3 += fmaxf(a2[mt2][r], 0.f) * w3v[mt2][r];

        t3 += __shfl_xor(t3, 16);
        t3 += __shfl_xor(t3, 32);

        if (lane < 16) out[p0] = 1.f / (1.f + expf(-t3));
    }
}

// ---------------------------------------------------------------------------
extern "C" void kernel_launch(void* const* d_in, const int* in_sizes, int n_in,
                              void* d_out, int out_size, void* d_ws, size_t ws_size,
                              hipStream_t stream)
{
    const float* x     = (const float*)d_in[0];
    const int*   ei    = (const int*)d_in[1];
    const int*   ep    = (const int*)d_in[2];
    const float* c1_Wl = (const float*)d_in[3];
    const float* c1_bl = (const float*)d_in[4];
    const float* c1_Wr = (const float*)d_in[5];
    const float* bn_g  = (const float*)d_in[6];
    const float* bn_b  = (const float*)d_in[7];
    const float* bn_m  = (const float*)d_in[8];
    const float* bn_v  = (const float*)d_in[9];
    const float* c2_Wl = (const float*)d_in[10];
    const float* c2_bl = (const float*)d_in[11];
    const float* c2_Wr = (const float*)d_in[12];
    const float* e_W1  = (const float*)d_in[13];
    const float* e_b1  = (const float*)d_in[14];
    const float* e_W2  = (const float*)d_in[15];
    const float* e_b2  = (const float*)d_in[16];
    const float* e_W3  = (const float*)d_in[17];
    const float* e_b3  = (const float*)d_in[18];
    float* out = (float*)d_out;

    // ws layout (halfs): xh[6.4M] | meanh[6.4M] | hh[6.4M] | zbf[3.2M]
    //                  | w1cat[32768] | w2cat[16384] | w1bf[8192] | w2bf[2048]
    //                  | bnsc/bnsh f32[256] | CSR ints
    _Float16* xh    = (_Float16*)d_ws;
    _Float16* meanh = xh + (size_t)NN * DIN;
    _Float16* hh    = meanh + (size_t)NN * DIN;
    ushort_t* zbf   = (ushort_t*)(hh + (size_t)NN * DHID);
    _Float16* w1cat = (_Float16*)(zbf + (size_t)NN * DOUT);
    _Float16* w2cat = w1cat + 128 * 256;
    ushort_t* w1bf  = (ushort_t*)(w2cat + 64 * 256);
    ushort_t* w2bf  = w1bf + 64 * 128;
    float*    bnsc  = (float*)(w2bf + 32 * 64);
    float*    bnsh  = bnsc + 128;
    int*      deg     = (int*)(bnsh + 128);
    int*      cursor  = deg + 50048;
    int*      rowptr  = cursor + 50048;
    int*      csr_src = rowptr + 50052;

    hipMemsetAsync(deg, 0, (size_t)(50048 * 2) * sizeof(int), stream);

    k_deg <<<3125, 256, 0, stream>>>(ei, deg);
    k_scan<<<1, 1024, 0, stream>>>(deg, rowptr);
    k_fill<<<3125, 256, 0, stream>>>(ei, rowptr, cursor, csr_src);
    k_prep<<<1, 256, 0, stream>>>(c1_Wl, c1_Wr, c2_Wl, c2_Wr,
                                  bn_g, bn_b, bn_m, bn_v, e_W1, e_W2,
                                  w1cat, w2cat, w1bf, w2bf, bnsc, bnsh);
    k_xcast<<<3125, 256, 0, stream>>>(x, xh);

    k_gather_mean_h<<<12500, 256, 0, stream>>>(xh, rowptr, csr_src, meanh);
    k_conv1_mfma<<<3125, 256, 0, stream>>>(xh, meanh, w1cat, c1_bl, bnsc, bnsh, hh);

    k_gather_mean_h<<<12500, 256, 0, stream>>>(hh, rowptr, csr_src, meanh);
    k_conv2_mfma<<<3125, 256, 0, stream>>>(hh, meanh, w2cat, c2_bl, zbf);

    k_edge<<<1024, 256, 0, stream>>>(zbf, ep, w1bf, e_b1, w2bf, e_b2,
                                     e_W3, e_b3, out);
}

// Round 7
// 315.834 us; speedup vs baseline: 11.4035x; 1.2217x over previous
//
#include <hip/hip_runtime.h>
#include <math.h>

#define NN 50000
#define NE 800000
#define DIN 128
#define DHID 128
#define DOUT 64
#define BN_EPS 1e-5f

typedef __attribute__((ext_vector_type(8))) short bf16x8;
typedef __attribute__((ext_vector_type(8))) _Float16 f16x8;
typedef __attribute__((ext_vector_type(4))) _Float16 f16x4;
typedef __attribute__((ext_vector_type(2))) _Float16 f16x2;
typedef __attribute__((ext_vector_type(4))) float f32x4;
typedef unsigned short ushort_t;
typedef unsigned int uint_t;

__device__ __forceinline__ ushort_t f2bf(float f) {
    uint_t u = __float_as_uint(f);
    uint_t r = (u + 0x7FFFu + ((u >> 16) & 1u)) >> 16;   // round-to-nearest-even
    return (ushort_t)r;
}

// ---------------------------------------------------------------------------
// CSR build: histogram of dst degrees.
__global__ __launch_bounds__(256) void k_deg(const int* __restrict__ ei, int* __restrict__ deg)
{
    int e = blockIdx.x * blockDim.x + threadIdx.x;
    if (e >= NE) return;
    atomicAdd(deg + ei[NE + e], 1);
}

// Scan stage 1: 49 blocks, each sums 1024 deg elems (int4 coalesced) -> part[b].
__global__ __launch_bounds__(256) void k_scan1(const int* __restrict__ deg, int* __restrict__ part)
{
    __shared__ int s[256];
    int t = threadIdx.x;
    int g = blockIdx.x * 256 + t;
    int v = 0;
    if (g < 12500) { int4 d = ((const int4*)deg)[g]; v = d.x + d.y + d.z + d.w; }
    s[t] = v;
    __syncthreads();
    #pragma unroll
    for (int off = 128; off > 0; off >>= 1) {
        if (t < off) s[t] += s[t + off];
        __syncthreads();
    }
    if (t == 0) part[blockIdx.x] = s[0];
}

// Scan stage 2: per-block exclusive scan (int4 coalesced in/out) + block offset.
__global__ __launch_bounds__(256) void k_scan3(
    const int* __restrict__ deg, const int* __restrict__ part, int* __restrict__ rowptr)
{
    __shared__ int s[256];
    __shared__ int p[64];
    int t = threadIdx.x;
    int b = blockIdx.x;
    int g = b * 256 + t;
    int4 d = make_int4(0, 0, 0, 0);
    if (g < 12500) d = ((const int4*)deg)[g];
    int sum4 = d.x + d.y + d.z + d.w;
    s[t] = sum4;
    if (t < 49) p[t] = part[t];
    __syncthreads();
    #pragma unroll
    for (int off = 1; off < 256; off <<= 1) {   // inclusive Hillis-Steele
        int v = (t >= off) ? s[t - off] : 0;
        __syncthreads();
        s[t] += v;
        __syncthreads();
    }
    int blockoff = 0;
    for (int i = 0; i < b; ++i) blockoff += p[i];   // LDS broadcast reads
    int off0 = blockoff + s[t] - sum4;              // exclusive prefix for this int4
    if (g < 12500) {
        int4 o;
        o.x = off0;
        o.y = off0 + d.x;
        o.z = o.y + d.y;
        o.w = o.z + d.z;
        ((int4*)rowptr)[g] = o;
        if (g == 12499) rowptr[NN] = o.w + d.w;     // = NE
    }
}

// Fill CSR column (src) array.
__global__ __launch_bounds__(256) void k_fill(
    const int* __restrict__ ei, const int* __restrict__ rowptr,
    int* __restrict__ cursor, int* __restrict__ csr_src)
{
    int e = blockIdx.x * blockDim.x + threadIdx.x;
    if (e >= NE) return;
    int dst = ei[NE + e];
    int slot = atomicAdd(cursor + dst, 1);
    csr_src[rowptr[dst] + slot] = ei[e];
}

// ---------------------------------------------------------------------------
// Weight prep: conv weights -> fp16 concat [out][mean_k | root_k]; edge weights
// -> bf16; BN folded to scale/shift.
__global__ __launch_bounds__(256) void k_prep(
    const float* __restrict__ c1_Wl, const float* __restrict__ c1_Wr,
    const float* __restrict__ c2_Wl, const float* __restrict__ c2_Wr,
    const float* __restrict__ gam, const float* __restrict__ bet,
    const float* __restrict__ bmean, const float* __restrict__ bvar,
    const float* __restrict__ eW1, const float* __restrict__ eW2,
    _Float16* __restrict__ w1cat, _Float16* __restrict__ w2cat,
    ushort_t* __restrict__ w1bf, ushort_t* __restrict__ w2bf,
    float* __restrict__ bnsc, float* __restrict__ bnsh)
{
    int t = threadIdx.x;
    for (int i = t; i < 128 * 128; i += 256) {
        int row = i >> 7, k = i & 127;
        w1cat[row * 256 + k]       = (_Float16)c1_Wl[i];
        w1cat[row * 256 + 128 + k] = (_Float16)c1_Wr[i];
    }
    for (int i = t; i < 64 * 128; i += 256) {
        int row = i >> 7, k = i & 127;
        w2cat[row * 256 + k]       = (_Float16)c2_Wl[i];
        w2cat[row * 256 + 128 + k] = (_Float16)c2_Wr[i];
    }
    for (int i = t; i < 64 * 128; i += 256) w1bf[i] = f2bf(eW1[i]);
    for (int i = t; i < 32 * 64; i += 256)  w2bf[i] = f2bf(eW2[i]);
    for (int i = t; i < 128; i += 256) {
        float s = gam[i] * rsqrtf(bvar[i] + BN_EPS);
        bnsc[i] = s;
        bnsh[i] = bet[i] - bmean[i] * s;
    }
}

// Cast x (f32) -> fp16, 8 elems/thread.
__global__ __launch_bounds__(256) void k_xcast(const float* __restrict__ x, _Float16* __restrict__ xh)
{
    int i = blockIdx.x * blockDim.x + threadIdx.x;
    if (i >= NN * DIN / 8) return;
    const float4* src = (const float4*)x + (size_t)i * 2;
    float4 a = src[0], b = src[1];
    f16x8 o;
    o[0] = (_Float16)a.x; o[1] = (_Float16)a.y; o[2] = (_Float16)a.z; o[3] = (_Float16)a.w;
    o[4] = (_Float16)b.x; o[5] = (_Float16)b.y; o[6] = (_Float16)b.z; o[7] = (_Float16)b.w;
    *(f16x8*)(xh + (size_t)i * 8) = o;
}

// ---------------------------------------------------------------------------
// Gather-mean over CSR, fp16 in/out, f32 accumulate, 4-way unrolled for MLP.
__global__ __launch_bounds__(256) void k_gather_mean_h(
    const _Float16* __restrict__ feat, const int* __restrict__ rowptr,
    const int* __restrict__ csr_src, _Float16* __restrict__ mean)
{
    int wv = (blockIdx.x * blockDim.x + threadIdx.x) >> 6;
    int lane = threadIdx.x & 63;
    if (wv >= NN) return;
    int beg = rowptr[wv], end = rowptr[wv + 1];

    float2 a0 = {0.f, 0.f}, a1 = {0.f, 0.f}, a2 = {0.f, 0.f}, a3 = {0.f, 0.f};
    int j = beg;
    for (; j + 3 < end; j += 4) {
        int s0 = csr_src[j];
        int s1 = csr_src[j + 1];
        int s2 = csr_src[j + 2];
        int s3 = csr_src[j + 3];
        f16x2 v0 = *(const f16x2*)(feat + (size_t)s0 * 128 + lane * 2);
        f16x2 v1 = *(const f16x2*)(feat + (size_t)s1 * 128 + lane * 2);
        f16x2 v2 = *(const f16x2*)(feat + (size_t)s2 * 128 + lane * 2);
        f16x2 v3 = *(const f16x2*)(feat + (size_t)s3 * 128 + lane * 2);
        a0.x += (float)v0[0]; a0.y += (float)v0[1];
        a1.x += (float)v1[0]; a1.y += (float)v1[1];
        a2.x += (float)v2[0]; a2.y += (float)v2[1];
        a3.x += (float)v3[0]; a3.y += (float)v3[1];
    }
    for (; j < end; ++j) {
        int s0 = csr_src[j];
        f16x2 v0 = *(const f16x2*)(feat + (size_t)s0 * 128 + lane * 2);
        a0.x += (float)v0[0]; a0.y += (float)v0[1];
    }
    float inv = 1.0f / fmaxf((float)(end - beg), 1.0f);
    f16x2 o;
    o[0] = (_Float16)((a0.x + a1.x + a2.x + a3.x) * inv);
    o[1] = (_Float16)((a0.y + a1.y + a2.y + a3.y) * inv);
    *(f16x2*)(mean + (size_t)wv * 128 + lane * 2) = o;
}

// ---------------------------------------------------------------------------
// Conv1 via MFMA: h = relu(BN(mean@Wl.T + bl + x@Wr.T)), fp16 in, fp16 out.
__global__ __launch_bounds__(256) void k_conv1_mfma(
    const _Float16* __restrict__ xh, const _Float16* __restrict__ meanh,
    const _Float16* __restrict__ w1cat, const float* __restrict__ bl,
    const float* __restrict__ bnsc, const float* __restrict__ bnsh,
    _Float16* __restrict__ hh)
{
    const int tid = threadIdx.x;
    const int lane = tid & 63;
    const int e = lane & 15;
    const int c = lane >> 4;
    const int chunk = tid >> 6;        // 4 waves = 4 col-chunks of 32
    const int tile = blockIdx.x;       // 3125 tiles * 16 nodes = 50000 exact
    const int node = tile * 16 + e;

    f16x8 wf[2][8];
    #pragma unroll
    for (int nt = 0; nt < 2; ++nt)
        #pragma unroll
        for (int ks = 0; ks < 8; ++ks)
            wf[nt][ks] = *(const f16x8*)(w1cat + (size_t)(chunk * 32 + nt * 16 + e) * 256 + ks * 32 + c * 8);

    f32x4 acc[2];
    #pragma unroll
    for (int nt = 0; nt < 2; ++nt)
        acc[nt] = *(const f32x4*)(bl + chunk * 32 + nt * 16 + c * 4);

    f16x8 bf[8];
    #pragma unroll
    for (int ks = 0; ks < 4; ++ks)
        bf[ks] = *(const f16x8*)(meanh + (size_t)node * 128 + ks * 32 + c * 8);
    #pragma unroll
    for (int ks = 4; ks < 8; ++ks)
        bf[ks] = *(const f16x8*)(xh + (size_t)node * 128 + (ks - 4) * 32 + c * 8);

    #pragma unroll
    for (int ks = 0; ks < 8; ++ks)
        #pragma unroll
        for (int nt = 0; nt < 2; ++nt)
            acc[nt] = __builtin_amdgcn_mfma_f32_16x16x32_f16(wf[nt][ks], bf[ks], acc[nt], 0, 0, 0);

    #pragma unroll
    for (int nt = 0; nt < 2; ++nt) {
        int j0 = chunk * 32 + nt * 16 + c * 4;
        f32x4 sc = *(const f32x4*)(bnsc + j0);
        f32x4 sh = *(const f32x4*)(bnsh + j0);
        f16x4 o;
        #pragma unroll
        for (int r = 0; r < 4; ++r)
            o[r] = (_Float16)fmaxf(acc[nt][r] * sc[r] + sh[r], 0.f);
        *(f16x4*)(hh + (size_t)node * 128 + j0) = o;
    }
}

// Conv2 via MFMA: z = mean2@Wl.T + bl + h@Wr.T -> bf16.
__global__ __launch_bounds__(256) void k_conv2_mfma(
    const _Float16* __restrict__ hh, const _Float16* __restrict__ meanh,
    const _Float16* __restrict__ w2cat, const float* __restrict__ bl,
    ushort_t* __restrict__ zbf)
{
    const int tid = threadIdx.x;
    const int lane = tid & 63;
    const int e = lane & 15;
    const int c = lane >> 4;
    const int chunk = tid >> 6;        // 4 waves = 4 col-chunks of 16
    const int tile = blockIdx.x;
    const int node = tile * 16 + e;

    f16x8 wf[8];
    #pragma unroll
    for (int ks = 0; ks < 8; ++ks)
        wf[ks] = *(const f16x8*)(w2cat + (size_t)(chunk * 16 + e) * 256 + ks * 32 + c * 8);

    f32x4 acc = *(const f32x4*)(bl + chunk * 16 + c * 4);

    f16x8 bf[8];
    #pragma unroll
    for (int ks = 0; ks < 4; ++ks)
        bf[ks] = *(const f16x8*)(meanh + (size_t)node * 128 + ks * 32 + c * 8);
    #pragma unroll
    for (int ks = 4; ks < 8; ++ks)
        bf[ks] = *(const f16x8*)(hh + (size_t)node * 128 + (ks - 4) * 32 + c * 8);

    #pragma unroll
    for (int ks = 0; ks < 8; ++ks)
        acc = __builtin_amdgcn_mfma_f32_16x16x32_f16(wf[ks], bf[ks], acc, 0, 0, 0);

    int j0 = chunk * 16 + c * 4;
    uint2 pk;
    pk.x = (uint_t)f2bf(acc[0]) | ((uint_t)f2bf(acc[1]) << 16);
    pk.y = (uint_t)f2bf(acc[2]) | ((uint_t)f2bf(acc[3]) << 16);
    *(uint2*)(zbf + (size_t)node * 64 + j0) = pk;
}

// ---------------------------------------------------------------------------
// Edge head via MFMA, 16 edges per wave-tile.
__global__ __launch_bounds__(256, 2) void k_edge(
    const ushort_t* __restrict__ zbf, const int* __restrict__ ep,
    const ushort_t* __restrict__ w1bf, const float* __restrict__ b1,
    const ushort_t* __restrict__ w2bf, const float* __restrict__ b2,
    const float* __restrict__ W3, const float* __restrict__ b3,
    float* __restrict__ out)
{
    __shared__ ushort_t a1lds[4][16 * 64];   // 2 KB per wave
    const int tid  = threadIdx.x;
    const int lane = tid & 63;
    const int e    = lane & 15;
    const int c    = lane >> 4;
    ushort_t* lds  = &a1lds[tid >> 6][0];
    const uint_t swz = (uint_t)((e & 7) << 4);

    bf16x8 w1f[4][4];
    #pragma unroll
    for (int mt = 0; mt < 4; ++mt)
        #pragma unroll
        for (int ks = 0; ks < 4; ++ks)
            w1f[mt][ks] = *(const bf16x8*)(w1bf + (mt * 16 + e) * 128 + ks * 32 + c * 8);

    bf16x8 w2f[2][2];
    #pragma unroll
    for (int mt2 = 0; mt2 < 2; ++mt2)
        #pragma unroll
        for (int ks2 = 0; ks2 < 2; ++ks2)
            w2f[mt2][ks2] = *(const bf16x8*)(w2bf + (mt2 * 16 + e) * 64 + ks2 * 32 + c * 8);

    f32x4 bias1[4];
    #pragma unroll
    for (int mt = 0; mt < 4; ++mt) bias1[mt] = *(const f32x4*)(b1 + mt * 16 + c * 4);
    f32x4 bias2[2];
    #pragma unroll
    for (int mt2 = 0; mt2 < 2; ++mt2) bias2[mt2] = *(const f32x4*)(b2 + mt2 * 16 + c * 4);
    f32x4 w3v[2];
    #pragma unroll
    for (int mt2 = 0; mt2 < 2; ++mt2) w3v[mt2] = *(const f32x4*)(W3 + mt2 * 16 + c * 4);
    const float b3v = b3[0];

    const int nw = (gridDim.x * blockDim.x) >> 6;
    const int wv = (blockIdx.x * blockDim.x + tid) >> 6;
    const int NT = NE / 16;

    for (int tile = wv; tile < NT; tile += nw) {
        int p0 = tile * 16 + e;
        int ni = ep[p0];
        int nj = ep[NE + p0];
        const ushort_t* zi = zbf + (size_t)ni * DOUT;
        const ushort_t* zj = zbf + (size_t)nj * DOUT;

        bf16x8 bfr[4];
        bfr[0] = *(const bf16x8*)(zi + c * 8);
        bfr[1] = *(const bf16x8*)(zi + 32 + c * 8);
        bfr[2] = *(const bf16x8*)(zj + c * 8);
        bfr[3] = *(const bf16x8*)(zj + 32 + c * 8);

        f32x4 acc[4];
        #pragma unroll
        for (int mt = 0; mt < 4; ++mt) acc[mt] = bias1[mt];

        #pragma unroll
        for (int ks = 0; ks < 4; ++ks)
            #pragma unroll
            for (int mt = 0; mt < 4; ++mt)
                acc[mt] = __builtin_amdgcn_mfma_f32_16x16x32_bf16(w1f[mt][ks], bfr[ks], acc[mt], 0, 0, 0);

        #pragma unroll
        for (int mt = 0; mt < 4; ++mt) {
            uint_t lo = (uint_t)f2bf(fmaxf(acc[mt][0], 0.f)) | ((uint_t)f2bf(fmaxf(acc[mt][1], 0.f)) << 16);
            uint_t hi = (uint_t)f2bf(fmaxf(acc[mt][2], 0.f)) | ((uint_t)f2bf(fmaxf(acc[mt][3], 0.f)) << 16);
            uint_t off = (uint_t)(e * 128 + mt * 32 + c * 8) ^ swz;
            *(uint2*)((char*)lds + off) = make_uint2(lo, hi);
        }

        bf16x8 b2f[2];
        #pragma unroll
        for (int ks2 = 0; ks2 < 2; ++ks2) {
            uint_t off = (uint_t)(e * 128 + ks2 * 64 + c * 16) ^ swz;
            b2f[ks2] = *(const bf16x8*)((const char*)lds + off);
        }

        f32x4 a2[2];
        #pragma unroll
        for (int mt2 = 0; mt2 < 2; ++mt2) a2[mt2] = bias2[mt2];
        #pragma unroll
        for (int ks2 = 0; ks2 < 2; ++ks2)
            #pragma unroll
            for (int mt2 = 0; mt2 < 2; ++mt2)
                a2[mt2] = __builtin_amdgcn_mfma_f32_16x16x32_bf16(w2f[mt2][ks2], b2f[ks2], a2[mt2], 0, 0, 0);

        float t3 = b3v;
        #pragma unroll
        for (int mt2 = 0; mt2 < 2; ++mt2)
            #pragma unroll
            for (int r = 0; r < 4; ++r)
                t3 += fmaxf(a2[mt2][r], 0.f) * w3v[mt2][r];

        t3 += __shfl_xor(t3, 16);
        t3 += __shfl_xor(t3, 32);

        if (lane < 16) out[p0] = 1.f / (1.f + expf(-t3));
    }
}

// ---------------------------------------------------------------------------
extern "C" void kernel_launch(void* const* d_in, const int* in_sizes, int n_in,
                              void* d_out, int out_size, void* d_ws, size_t ws_size,
                              hipStream_t stream)
{
    const float* x     = (const float*)d_in[0];
    const int*   ei    = (const int*)d_in[1];
    const int*   ep    = (const int*)d_in[2];
    const float* c1_Wl = (const float*)d_in[3];
    const float* c1_bl = (const float*)d_in[4];
    const float* c1_Wr = (const float*)d_in[5];
    const float* bn_g  = (const float*)d_in[6];
    const float* bn_b  = (const float*)d_in[7];
    const float* bn_m  = (const float*)d_in[8];
    const float* bn_v  = (const float*)d_in[9];
    const float* c2_Wl = (const float*)d_in[10];
    const float* c2_bl = (const float*)d_in[11];
    const float* c2_Wr = (const float*)d_in[12];
    const float* e_W1  = (const float*)d_in[13];
    const float* e_b1  = (const float*)d_in[14];
    const float* e_W2  = (const float*)d_in[15];
    const float* e_b2  = (const float*)d_in[16];
    const float* e_W3  = (const float*)d_in[17];
    const float* e_b3  = (const float*)d_in[18];
    float* out = (float*)d_out;

    // ws layout (halfs): xh[6.4M] | meanh[6.4M] | hh[6.4M] | zbf[3.2M]
    //                  | w1cat[32768] | w2cat[16384] | w1bf[8192] | w2bf[2048]
    //                  | bnsc/bnsh f32[256] | CSR ints | part[64]
    _Float16* xh    = (_Float16*)d_ws;
    _Float16* meanh = xh + (size_t)NN * DIN;
    _Float16* hh    = meanh + (size_t)NN * DIN;
    ushort_t* zbf   = (ushort_t*)(hh + (size_t)NN * DHID);
    _Float16* w1cat = (_Float16*)(zbf + (size_t)NN * DOUT);
    _Float16* w2cat = w1cat + 128 * 256;
    ushort_t* w1bf  = (ushort_t*)(w2cat + 64 * 256);
    ushort_t* w2bf  = w1bf + 64 * 128;
    float*    bnsc  = (float*)(w2bf + 32 * 64);
    float*    bnsh  = bnsc + 128;
    int*      deg     = (int*)(bnsh + 128);
    int*      cursor  = deg + 50048;
    int*      rowptr  = cursor + 50048;
    int*      csr_src = rowptr + 50052;
    int*      part    = csr_src + 800000;

    hipMemsetAsync(deg, 0, (size_t)(50048 * 2) * sizeof(int), stream);

    k_deg  <<<3125, 256, 0, stream>>>(ei, deg);
    k_scan1<<<49, 256, 0, stream>>>(deg, part);
    k_scan3<<<49, 256, 0, stream>>>(deg, part, rowptr);
    k_fill <<<3125, 256, 0, stream>>>(ei, rowptr, cursor, csr_src);
    k_prep <<<1, 256, 0, stream>>>(c1_Wl, c1_Wr, c2_Wl, c2_Wr,
                                   bn_g, bn_b, bn_m, bn_v, e_W1, e_W2,
                                   w1cat, w2cat, w1bf, w2bf, bnsc, bnsh);
    k_xcast<<<3125, 256, 0, stream>>>(x, xh);

    k_gather_mean_h<<<12500, 256, 0, stream>>>(xh, rowptr, csr_src, meanh);
    k_conv1_mfma<<<3125, 256, 0, stream>>>(xh, meanh, w1cat, c1_bl, bnsc, bnsh, hh);

    k_gather_mean_h<<<12500, 256, 0, stream>>>(hh, rowptr, csr_src, meanh);
    k_conv2_mfma<<<3125, 256, 0, stream>>>(hh, meanh, w2cat, c2_bl, zbf);

    k_edge<<<1024, 256, 0, stream>>>(zbf, ep, w1bf, e_b1, w2bf, e_b2,
                                     e_W3, e_b3, out);
}

// Round 8
// 315.805 us; speedup vs baseline: 11.4046x; 1.0001x over previous
//
#include <hip/hip_runtime.h>
#include <math.h>

#define NN 50000
#define NE 800000
#define DIN 128
#define DHID 128
#define DOUT 64
#define BN_EPS 1e-5f

typedef __attribute__((ext_vector_type(8))) short bf16x8;
typedef __attribute__((ext_vector_type(8))) _Float16 f16x8;
typedef __attribute__((ext_vector_type(4))) _Float16 f16x4;
typedef __attribute__((ext_vector_type(2))) _Float16 f16x2;
typedef __attribute__((ext_vector_type(4))) float f32x4;
typedef unsigned short ushort_t;
typedef unsigned int uint_t;

__device__ __forceinline__ ushort_t f2bf(float f) {
    uint_t u = __float_as_uint(f);
    uint_t r = (u + 0x7FFFu + ((u >> 16) & 1u)) >> 16;   // round-to-nearest-even
    return (ushort_t)r;
}

// ---------------------------------------------------------------------------
// CSR build: histogram of dst degrees.
__global__ __launch_bounds__(256) void k_deg(const int* __restrict__ ei, int* __restrict__ deg)
{
    int e = blockIdx.x * blockDim.x + threadIdx.x;
    if (e >= NE) return;
    atomicAdd(deg + ei[NE + e], 1);
}

// Scan stage 1: 49 blocks, each sums 1024 deg elems (int4 coalesced) -> part[b].
__global__ __launch_bounds__(256) void k_scan1(const int* __restrict__ deg, int* __restrict__ part)
{
    __shared__ int s[256];
    int t = threadIdx.x;
    int g = blockIdx.x * 256 + t;
    int v = 0;
    if (g < 12500) { int4 d = ((const int4*)deg)[g]; v = d.x + d.y + d.z + d.w; }
    s[t] = v;
    __syncthreads();
    #pragma unroll
    for (int off = 128; off > 0; off >>= 1) {
        if (t < off) s[t] += s[t + off];
        __syncthreads();
    }
    if (t == 0) part[blockIdx.x] = s[0];
}

// Scan stage 2: per-block exclusive scan (int4 coalesced in/out) + block offset.
__global__ __launch_bounds__(256) void k_scan3(
    const int* __restrict__ deg, const int* __restrict__ part, int* __restrict__ rowptr)
{
    __shared__ int s[256];
    __shared__ int p[64];
    int t = threadIdx.x;
    int b = blockIdx.x;
    int g = b * 256 + t;
    int4 d = make_int4(0, 0, 0, 0);
    if (g < 12500) d = ((const int4*)deg)[g];
    int sum4 = d.x + d.y + d.z + d.w;
    s[t] = sum4;
    if (t < 49) p[t] = part[t];
    __syncthreads();
    #pragma unroll
    for (int off = 1; off < 256; off <<= 1) {   // inclusive Hillis-Steele
        int v = (t >= off) ? s[t - off] : 0;
        __syncthreads();
        s[t] += v;
        __syncthreads();
    }
    int blockoff = 0;
    for (int i = 0; i < b; ++i) blockoff += p[i];   // LDS broadcast reads
    int off0 = blockoff + s[t] - sum4;              // exclusive prefix for this int4
    if (g < 12500) {
        int4 o;
        o.x = off0;
        o.y = off0 + d.x;
        o.z = o.y + d.y;
        o.w = o.z + d.z;
        ((int4*)rowptr)[g] = o;
        if (g == 12499) rowptr[NN] = o.w + d.w;     // = NE
    }
}

// Fill CSR column (src) array.
__global__ __launch_bounds__(256) void k_fill(
    const int* __restrict__ ei, const int* __restrict__ rowptr,
    int* __restrict__ cursor, int* __restrict__ csr_src)
{
    int e = blockIdx.x * blockDim.x + threadIdx.x;
    if (e >= NE) return;
    int dst = ei[NE + e];
    int slot = atomicAdd(cursor + dst, 1);
    csr_src[rowptr[dst] + slot] = ei[e];
}

// ---------------------------------------------------------------------------
// Weight prep: conv weights -> fp16 concat [out][mean_k | root_k]; edge weights
// -> bf16; BN folded to scale/shift.
__global__ __launch_bounds__(256) void k_prep(
    const float* __restrict__ c1_Wl, const float* __restrict__ c1_Wr,
    const float* __restrict__ c2_Wl, const float* __restrict__ c2_Wr,
    const float* __restrict__ gam, const float* __restrict__ bet,
    const float* __restrict__ bmean, const float* __restrict__ bvar,
    const float* __restrict__ eW1, const float* __restrict__ eW2,
    _Float16* __restrict__ w1cat, _Float16* __restrict__ w2cat,
    ushort_t* __restrict__ w1bf, ushort_t* __restrict__ w2bf,
    float* __restrict__ bnsc, float* __restrict__ bnsh)
{
    int t = threadIdx.x;
    for (int i = t; i < 128 * 128; i += 256) {
        int row = i >> 7, k = i & 127;
        w1cat[row * 256 + k]       = (_Float16)c1_Wl[i];
        w1cat[row * 256 + 128 + k] = (_Float16)c1_Wr[i];
    }
    for (int i = t; i < 64 * 128; i += 256) {
        int row = i >> 7, k = i & 127;
        w2cat[row * 256 + k]       = (_Float16)c2_Wl[i];
        w2cat[row * 256 + 128 + k] = (_Float16)c2_Wr[i];
    }
    for (int i = t; i < 64 * 128; i += 256) w1bf[i] = f2bf(eW1[i]);
    for (int i = t; i < 32 * 64; i += 256)  w2bf[i] = f2bf(eW2[i]);
    for (int i = t; i < 128; i += 256) {
        float s = gam[i] * rsqrtf(bvar[i] + BN_EPS);
        bnsc[i] = s;
        bnsh[i] = bet[i] - bmean[i] * s;
    }
}

// Cast x (f32) -> fp16, 8 elems/thread.
__global__ __launch_bounds__(256) void k_xcast(const float* __restrict__ x, _Float16* __restrict__ xh)
{
    int i = blockIdx.x * blockDim.x + threadIdx.x;
    if (i >= NN * DIN / 8) return;
    const float4* src = (const float4*)x + (size_t)i * 2;
    float4 a = src[0], b = src[1];
    f16x8 o;
    o[0] = (_Float16)a.x; o[1] = (_Float16)a.y; o[2] = (_Float16)a.z; o[3] = (_Float16)a.w;
    o[4] = (_Float16)b.x; o[5] = (_Float16)b.y; o[6] = (_Float16)b.z; o[7] = (_Float16)b.w;
    *(f16x8*)(xh + (size_t)i * 8) = o;
}

// ---------------------------------------------------------------------------
// Gather-mean over CSR, fp16 in/out, f32 accumulate, 8-way unrolled (mean deg=16
// -> 2 serial rounds of L3 latency instead of 4).
__global__ __launch_bounds__(256) void k_gather_mean_h(
    const _Float16* __restrict__ feat, const int* __restrict__ rowptr,
    const int* __restrict__ csr_src, _Float16* __restrict__ mean)
{
    int wv = (blockIdx.x * blockDim.x + threadIdx.x) >> 6;
    int lane = threadIdx.x & 63;
    if (wv >= NN) return;
    int beg = rowptr[wv], end = rowptr[wv + 1];

    float2 a0 = {0.f, 0.f}, a1 = {0.f, 0.f}, a2 = {0.f, 0.f}, a3 = {0.f, 0.f};
    float2 a4 = {0.f, 0.f}, a5 = {0.f, 0.f}, a6 = {0.f, 0.f}, a7 = {0.f, 0.f};
    int j = beg;
    for (; j + 7 < end; j += 8) {
        int s0 = csr_src[j];
        int s1 = csr_src[j + 1];
        int s2 = csr_src[j + 2];
        int s3 = csr_src[j + 3];
        int s4 = csr_src[j + 4];
        int s5 = csr_src[j + 5];
        int s6 = csr_src[j + 6];
        int s7 = csr_src[j + 7];
        f16x2 v0 = *(const f16x2*)(feat + (size_t)s0 * 128 + lane * 2);
        f16x2 v1 = *(const f16x2*)(feat + (size_t)s1 * 128 + lane * 2);
        f16x2 v2 = *(const f16x2*)(feat + (size_t)s2 * 128 + lane * 2);
        f16x2 v3 = *(const f16x2*)(feat + (size_t)s3 * 128 + lane * 2);
        f16x2 v4 = *(const f16x2*)(feat + (size_t)s4 * 128 + lane * 2);
        f16x2 v5 = *(const f16x2*)(feat + (size_t)s5 * 128 + lane * 2);
        f16x2 v6 = *(const f16x2*)(feat + (size_t)s6 * 128 + lane * 2);
        f16x2 v7 = *(const f16x2*)(feat + (size_t)s7 * 128 + lane * 2);
        a0.x += (float)v0[0]; a0.y += (float)v0[1];
        a1.x += (float)v1[0]; a1.y += (float)v1[1];
        a2.x += (float)v2[0]; a2.y += (float)v2[1];
        a3.x += (float)v3[0]; a3.y += (float)v3[1];
        a4.x += (float)v4[0]; a4.y += (float)v4[1];
        a5.x += (float)v5[0]; a5.y += (float)v5[1];
        a6.x += (float)v6[0]; a6.y += (float)v6[1];
        a7.x += (float)v7[0]; a7.y += (float)v7[1];
    }
    for (; j + 1 < end; j += 2) {
        int s0 = csr_src[j];
        int s1 = csr_src[j + 1];
        f16x2 v0 = *(const f16x2*)(feat + (size_t)s0 * 128 + lane * 2);
        f16x2 v1 = *(const f16x2*)(feat + (size_t)s1 * 128 + lane * 2);
        a0.x += (float)v0[0]; a0.y += (float)v0[1];
        a1.x += (float)v1[0]; a1.y += (float)v1[1];
    }
    if (j < end) {
        int s0 = csr_src[j];
        f16x2 v0 = *(const f16x2*)(feat + (size_t)s0 * 128 + lane * 2);
        a0.x += (float)v0[0]; a0.y += (float)v0[1];
    }
    float inv = 1.0f / fmaxf((float)(end - beg), 1.0f);
    f16x2 o;
    o[0] = (_Float16)((a0.x + a1.x + a2.x + a3.x + a4.x + a5.x + a6.x + a7.x) * inv);
    o[1] = (_Float16)((a0.y + a1.y + a2.y + a3.y + a4.y + a5.y + a6.y + a7.y) * inv);
    *(f16x2*)(mean + (size_t)wv * 128 + lane * 2) = o;
}

// ---------------------------------------------------------------------------
// Conv1 via MFMA: h = relu(BN(mean@Wl.T + bl + x@Wr.T)), fp16 in, fp16 out.
__global__ __launch_bounds__(256) void k_conv1_mfma(
    const _Float16* __restrict__ xh, const _Float16* __restrict__ meanh,
    const _Float16* __restrict__ w1cat, const float* __restrict__ bl,
    const float* __restrict__ bnsc, const float* __restrict__ bnsh,
    _Float16* __restrict__ hh)
{
    const int tid = threadIdx.x;
    const int lane = tid & 63;
    const int e = lane & 15;
    const int c = lane >> 4;
    const int chunk = tid >> 6;        // 4 waves = 4 col-chunks of 32
    const int tile = blockIdx.x;       // 3125 tiles * 16 nodes = 50000 exact
    const int node = tile * 16 + e;

    f16x8 wf[2][8];
    #pragma unroll
    for (int nt = 0; nt < 2; ++nt)
        #pragma unroll
        for (int ks = 0; ks < 8; ++ks)
            wf[nt][ks] = *(const f16x8*)(w1cat + (size_t)(chunk * 32 + nt * 16 + e) * 256 + ks * 32 + c * 8);

    f32x4 acc[2];
    #pragma unroll
    for (int nt = 0; nt < 2; ++nt)
        acc[nt] = *(const f32x4*)(bl + chunk * 32 + nt * 16 + c * 4);

    f16x8 bf[8];
    #pragma unroll
    for (int ks = 0; ks < 4; ++ks)
        bf[ks] = *(const f16x8*)(meanh + (size_t)node * 128 + ks * 32 + c * 8);
    #pragma unroll
    for (int ks = 4; ks < 8; ++ks)
        bf[ks] = *(const f16x8*)(xh + (size_t)node * 128 + (ks - 4) * 32 + c * 8);

    #pragma unroll
    for (int ks = 0; ks < 8; ++ks)
        #pragma unroll
        for (int nt = 0; nt < 2; ++nt)
            acc[nt] = __builtin_amdgcn_mfma_f32_16x16x32_f16(wf[nt][ks], bf[ks], acc[nt], 0, 0, 0);

    #pragma unroll
    for (int nt = 0; nt < 2; ++nt) {
        int j0 = chunk * 32 + nt * 16 + c * 4;
        f32x4 sc = *(const f32x4*)(bnsc + j0);
        f32x4 sh = *(const f32x4*)(bnsh + j0);
        f16x4 o;
        #pragma unroll
        for (int r = 0; r < 4; ++r)
            o[r] = (_Float16)fmaxf(acc[nt][r] * sc[r] + sh[r], 0.f);
        *(f16x4*)(hh + (size_t)node * 128 + j0) = o;
    }
}

// Conv2 via MFMA: z = mean2@Wl.T + bl + h@Wr.T -> bf16.
__global__ __launch_bounds__(256) void k_conv2_mfma(
    const _Float16* __restrict__ hh, const _Float16* __restrict__ meanh,
    const _Float16* __restrict__ w2cat, const float* __restrict__ bl,
    ushort_t* __restrict__ zbf)
{
    const int tid = threadIdx.x;
    const int lane = tid & 63;
    const int e = lane & 15;
    const int c = lane >> 4;
    const int chunk = tid >> 6;        // 4 waves = 4 col-chunks of 16
    const int tile = blockIdx.x;
    const int node = tile * 16 + e;

    f16x8 wf[8];
    #pragma unroll
    for (int ks = 0; ks < 8; ++ks)
        wf[ks] = *(const f16x8*)(w2cat + (size_t)(chunk * 16 + e) * 256 + ks * 32 + c * 8);

    f32x4 acc = *(const f32x4*)(bl + chunk * 16 + c * 4);

    f16x8 bf[8];
    #pragma unroll
    for (int ks = 0; ks < 4; ++ks)
        bf[ks] = *(const f16x8*)(meanh + (size_t)node * 128 + ks * 32 + c * 8);
    #pragma unroll
    for (int ks = 4; ks < 8; ++ks)
        bf[ks] = *(const f16x8*)(hh + (size_t)node * 128 + (ks - 4) * 32 + c * 8);

    #pragma unroll
    for (int ks = 0; ks < 8; ++ks)
        acc = __builtin_amdgcn_mfma_f32_16x16x32_f16(wf[ks], bf[ks], acc, 0, 0, 0);

    int j0 = chunk * 16 + c * 4;
    uint2 pk;
    pk.x = (uint_t)f2bf(acc[0]) | ((uint_t)f2bf(acc[1]) << 16);
    pk.y = (uint_t)f2bf(acc[2]) | ((uint_t)f2bf(acc[3]) << 16);
    *(uint2*)(zbf + (size_t)node * 64 + j0) = pk;
}

// ---------------------------------------------------------------------------
// Edge head via MFMA: 4 tiles per wave, double-buffered z prefetch.
// 3125 blocks * 4 waves = 12500 waves * 4 tiles = 50000 tiles.
__global__ __launch_bounds__(256) void k_edge(
    const ushort_t* __restrict__ zbf, const int* __restrict__ ep,
    const ushort_t* __restrict__ w1bf, const float* __restrict__ b1,
    const ushort_t* __restrict__ w2bf, const float* __restrict__ b2,
    const float* __restrict__ W3, const float* __restrict__ b3,
    float* __restrict__ out)
{
    __shared__ ushort_t a1lds[4][16 * 64];   // 2 KB per wave
    const int tid  = threadIdx.x;
    const int lane = tid & 63;
    const int e    = lane & 15;
    const int c    = lane >> 4;
    ushort_t* lds  = &a1lds[tid >> 6][0];
    const uint_t swz = (uint_t)((e & 7) << 4);

    bf16x8 w1f[4][4];
    #pragma unroll
    for (int mt = 0; mt < 4; ++mt)
        #pragma unroll
        for (int ks = 0; ks < 4; ++ks)
            w1f[mt][ks] = *(const bf16x8*)(w1bf + (mt * 16 + e) * 128 + ks * 32 + c * 8);

    bf16x8 w2f[2][2];
    #pragma unroll
    for (int mt2 = 0; mt2 < 2; ++mt2)
        #pragma unroll
        for (int ks2 = 0; ks2 < 2; ++ks2)
            w2f[mt2][ks2] = *(const bf16x8*)(w2bf + (mt2 * 16 + e) * 64 + ks2 * 32 + c * 8);

    f32x4 bias1[4];
    #pragma unroll
    for (int mt = 0; mt < 4; ++mt) bias1[mt] = *(const f32x4*)(b1 + mt * 16 + c * 4);
    f32x4 bias2[2];
    #pragma unroll
    for (int mt2 = 0; mt2 < 2; ++mt2) bias2[mt2] = *(const f32x4*)(b2 + mt2 * 16 + c * 4);
    f32x4 w3v[2];
    #pragma unroll
    for (int mt2 = 0; mt2 < 2; ++mt2) w3v[mt2] = *(const f32x4*)(W3 + mt2 * 16 + c * 4);
    const float b3v = b3[0];

    const int wv = (blockIdx.x * blockDim.x + tid) >> 6;   // 0..12499
    const int pbase = wv * 64 + e;                          // 4 tiles of 16 edges

#define LOADZ(T, dst)                                                         \
    {                                                                         \
        int p = pbase + (T) * 16;                                             \
        int ni = ep[p];                                                       \
        int nj = ep[NE + p];                                                  \
        const ushort_t* zi = zbf + (size_t)ni * DOUT;                         \
        const ushort_t* zj = zbf + (size_t)nj * DOUT;                         \
        dst[0] = *(const bf16x8*)(zi + c * 8);                                \
        dst[1] = *(const bf16x8*)(zi + 32 + c * 8);                           \
        dst[2] = *(const bf16x8*)(zj + c * 8);                                \
        dst[3] = *(const bf16x8*)(zj + 32 + c * 8);                           \
    }

#define COMPUTE(T, bfr)                                                       \
    {                                                                         \
        f32x4 acc[4];                                                         \
        _Pragma("unroll")                                                     \
        for (int mt = 0; mt < 4; ++mt) acc[mt] = bias1[mt];                   \
        _Pragma("unroll")                                                     \
        for (int ks = 0; ks < 4; ++ks)                                        \
            _Pragma("unroll")                                                 \
            for (int mt = 0; mt < 4; ++mt)                                    \
                acc[mt] = __builtin_amdgcn_mfma_f32_16x16x32_bf16(            \
                    w1f[mt][ks], bfr[ks], acc[mt], 0, 0, 0);                  \
        _Pragma("unroll")                                                     \
        for (int mt = 0; mt < 4; ++mt) {                                      \
            uint_t lo = (uint_t)f2bf(fmaxf(acc[mt][0], 0.f)) |                \
                        ((uint_t)f2bf(fmaxf(acc[mt][1], 0.f)) << 16);         \
            uint_t hi = (uint_t)f2bf(fmaxf(acc[mt][2], 0.f)) |                \
                        ((uint_t)f2bf(fmaxf(acc[mt][3], 0.f)) << 16);         \
            uint_t off = (uint_t)(e * 128 + mt * 32 + c * 8) ^ swz;           \
            *(uint2*)((char*)lds + off) = make_uint2(lo, hi);                 \
        }                                                                     \
        bf16x8 b2f[2];                                                        \
        _Pragma("unroll")                                                     \
        for (int ks2 = 0; ks2 < 2; ++ks2) {                                   \
            uint_t off = (uint_t)(e * 128 + ks2 * 64 + c * 16) ^ swz;         \
            b2f[ks2] = *(const bf16x8*)((const char*)lds + off);              \
        }                                                                     \
        f32x4 a2[2];                                                          \
        _Pragma("unroll")                                                     \
        for (int mt2 = 0; mt2 < 2; ++mt2) a2[mt2] = bias2[mt2];               \
        _Pragma("unroll")                                                     \
        for (int ks2 = 0; ks2 < 2; ++ks2)                                     \
            _Pragma("unroll")                                                 \
            for (int mt2 = 0; mt2 < 2; ++mt2)                                 \
                a2[mt2] = __builtin_amdgcn_mfma_f32_16x16x32_bf16(            \
                    w2f[mt2][ks2], b2f[ks2], a2[mt2], 0, 0, 0);               \
        float t3 = b3v;                                                       \
        _Pragma("unroll")                                                     \
        for (int mt2 = 0; mt2 < 2; ++mt2)                                     \
            _Pragma("unroll")                                                 \
            for (int r = 0; r < 4; ++r)                                       \
                t3 += fmaxf(a2[mt2][r], 0.f) * w3v[mt2][r];                   \
        t3 += __shfl_xor(t3, 16);                                             \
        t3 += __shfl_xor(t3, 32);                                             \
        if (lane < 16) out[pbase + (T) * 16] = 1.f / (1.f + expf(-t3));       \
    }

    bf16x8 z0[4], z1[4];
    LOADZ(0, z0);
    LOADZ(1, z1);      // prefetch tile 1 before computing tile 0
    COMPUTE(0, z0);
    LOADZ(2, z0);      // prefetch tile 2 under tile 1's compute
    COMPUTE(1, z1);
    LOADZ(3, z1);      // prefetch tile 3 under tile 2's compute
    COMPUTE(2, z0);
    COMPUTE(3, z1);

#undef LOADZ
#undef COMPUTE
}

// ---------------------------------------------------------------------------
extern "C" void kernel_launch(void* const* d_in, const int* in_sizes, int n_in,
                              void* d_out, int out_size, void* d_ws, size_t ws_size,
                              hipStream_t stream)
{
    const float* x     = (const float*)d_in[0];
    const int*   ei    = (const int*)d_in[1];
    const int*   ep    = (const int*)d_in[2];
    const float* c1_Wl = (const float*)d_in[3];
    const float* c1_bl = (const float*)d_in[4];
    const float* c1_Wr = (const float*)d_in[5];
    const float* bn_g  = (const float*)d_in[6];
    const float* bn_b  = (const float*)d_in[7];
    const float* bn_m  = (const float*)d_in[8];
    const float* bn_v  = (const float*)d_in[9];
    const float* c2_Wl = (const float*)d_in[10];
    const float* c2_bl = (const float*)d_in[11];
    const float* c2_Wr = (const float*)d_in[12];
    const float* e_W1  = (const float*)d_in[13];
    const float* e_b1  = (const float*)d_in[14];
    const float* e_W2  = (const float*)d_in[15];
    const float* e_b2  = (const float*)d_in[16];
    const float* e_W3  = (const float*)d_in[17];
    const float* e_b3  = (const float*)d_in[18];
    float* out = (float*)d_out;

    // ws layout (halfs): xh[6.4M] | meanh[6.4M] | hh[6.4M] | zbf[3.2M]
    //                  | w1cat[32768] | w2cat[16384] | w1bf[8192] | w2bf[2048]
    //                  | bnsc/bnsh f32[256] | CSR ints | part[64]
    _Float16* xh    = (_Float16*)d_ws;
    _Float16* meanh = xh + (size_t)NN * DIN;
    _Float16* hh    = meanh + (size_t)NN * DIN;
    ushort_t* zbf   = (ushort_t*)(hh + (size_t)NN * DHID);
    _Float16* w1cat = (_Float16*)(zbf + (size_t)NN * DOUT);
    _Float16* w2cat = w1cat + 128 * 256;
    ushort_t* w1bf  = (ushort_t*)(w2cat + 64 * 256);
    ushort_t* w2bf  = w1bf + 64 * 128;
    float*    bnsc  = (float*)(w2bf + 32 * 64);
    float*    bnsh  = bnsc + 128;
    int*      deg     = (int*)(bnsh + 128);
    int*      cursor  = deg + 50048;
    int*      rowptr  = cursor + 50048;
    int*      csr_src = rowptr + 50052;
    int*      part    = csr_src + 800000;

    hipMemsetAsync(deg, 0, (size_t)(50048 * 2) * sizeof(int), stream);

    k_deg  <<<3125, 256, 0, stream>>>(ei, deg);
    k_scan1<<<49, 256, 0, stream>>>(deg, part);
    k_scan3<<<49, 256, 0, stream>>>(deg, part, rowptr);
    k_fill <<<3125, 256, 0, stream>>>(ei, rowptr, cursor, csr_src);
    k_prep <<<1, 256, 0, stream>>>(c1_Wl, c1_Wr, c2_Wl, c2_Wr,
                                   bn_g, bn_b, bn_m, bn_v, e_W1, e_W2,
                                   w1cat, w2cat, w1bf, w2bf, bnsc, bnsh);
    k_xcast<<<3125, 256, 0, stream>>>(x, xh);

    k_gather_mean_h<<<12500, 256, 0, stream>>>(xh, rowptr, csr_src, meanh);
    k_conv1_mfma<<<3125, 256, 0, stream>>>(xh, meanh, w1cat, c1_bl, bnsc, bnsh, hh);

    k_gather_mean_h<<<12500, 256, 0, stream>>>(hh, rowptr, csr_src, meanh);
    k_conv2_mfma<<<3125, 256, 0, stream>>>(hh, meanh, w2cat, c2_bl, zbf);

    k_edge<<<3125, 256, 0, stream>>>(zbf, ep, w1bf, e_b1, w2bf, e_b2,
                                     e_W3, e_b3, out);
}

// Round 9
// 303.045 us; speedup vs baseline: 11.8848x; 1.0421x over previous
//
#include <hip/hip_runtime.h>
#include <hip/hip_bf16.h>
#include <math.h>

#define NN 50000
#define NE 800000
#define DIN 128
#define DHID 128
#define DOUT 64
#define BN_EPS 1e-5f

typedef __attribute__((ext_vector_type(8))) short bf16x8;
typedef __attribute__((ext_vector_type(8))) _Float16 f16x8;
typedef __attribute__((ext_vector_type(4))) _Float16 f16x4;
typedef __attribute__((ext_vector_type(2))) _Float16 f16x2;
typedef __attribute__((ext_vector_type(4))) float f32x4;
typedef unsigned short ushort_t;
typedef unsigned int uint_t;

__device__ __forceinline__ ushort_t f2bf(float f) {
    uint_t u = __float_as_uint(f);
    uint_t r = (u + 0x7FFFu + ((u >> 16) & 1u)) >> 16;   // RNE
    return (ushort_t)r;
}

// Hardware-cvt pair pack (compiler lowers __float2bfloat16 to v_cvt; m240: don't hand-write asm)
__device__ __forceinline__ uint_t pk2bf(float a, float b) {
    __hip_bfloat16 x = __float2bfloat16(a);
    __hip_bfloat16 y = __float2bfloat16(b);
    ushort_t ux = *reinterpret_cast<ushort_t*>(&x);
    ushort_t uy = *reinterpret_cast<ushort_t*>(&y);
    return (uint_t)ux | ((uint_t)uy << 16);
}

// ---------------------------------------------------------------------------
// Fused: blocks [0,3125) histogram dst degrees; blocks [3125,6250) cast x->fp16.
// Both sides are exactly 3125*256 = 800000 threads of work.
__global__ __launch_bounds__(256) void k_deg_xcast(
    const int* __restrict__ ei, int* __restrict__ deg,
    const float* __restrict__ x, _Float16* __restrict__ xh)
{
    int b = blockIdx.x;
    if (b < 3125) {
        int e = b * 256 + threadIdx.x;
        atomicAdd(deg + ei[NE + e], 1);
    } else {
        int i = (b - 3125) * 256 + threadIdx.x;   // < 800000 = NN*DIN/8
        const float4* src = (const float4*)x + (size_t)i * 2;
        float4 a = src[0], c = src[1];
        f16x8 o;
        o[0] = (_Float16)a.x; o[1] = (_Float16)a.y; o[2] = (_Float16)a.z; o[3] = (_Float16)a.w;
        o[4] = (_Float16)c.x; o[5] = (_Float16)c.y; o[6] = (_Float16)c.z; o[7] = (_Float16)c.w;
        *(f16x8*)(xh + (size_t)i * 8) = o;
    }
}

// ---------------------------------------------------------------------------
// Scan stage 1 (blocks 0..48): block-sum of deg (int4 coalesced) -> part[b].
// Block 49: weight prep (independent work, fused to save a launch).
__global__ __launch_bounds__(256) void k_scan1_prep(
    const int* __restrict__ deg, int* __restrict__ part,
    const float* __restrict__ c1_Wl, const float* __restrict__ c1_Wr,
    const float* __restrict__ c2_Wl, const float* __restrict__ c2_Wr,
    const float* __restrict__ gam, const float* __restrict__ bet,
    const float* __restrict__ bmean, const float* __restrict__ bvar,
    const float* __restrict__ eW1, const float* __restrict__ eW2,
    _Float16* __restrict__ w1cat, _Float16* __restrict__ w2cat,
    ushort_t* __restrict__ w1bf, ushort_t* __restrict__ w2bf,
    float* __restrict__ bnsc, float* __restrict__ bnsh)
{
    int t = threadIdx.x;
    if (blockIdx.x < 49) {
        __shared__ int s[256];
        int g = blockIdx.x * 256 + t;
        int v = 0;
        if (g < 12500) { int4 d = ((const int4*)deg)[g]; v = d.x + d.y + d.z + d.w; }
        s[t] = v;
        __syncthreads();
        #pragma unroll
        for (int off = 128; off > 0; off >>= 1) {
            if (t < off) s[t] += s[t + off];
            __syncthreads();
        }
        if (t == 0) part[blockIdx.x] = s[0];
    } else {
        for (int i = t; i < 128 * 128; i += 256) {
            int row = i >> 7, k = i & 127;
            w1cat[row * 256 + k]       = (_Float16)c1_Wl[i];
            w1cat[row * 256 + 128 + k] = (_Float16)c1_Wr[i];
        }
        for (int i = t; i < 64 * 128; i += 256) {
            int row = i >> 7, k = i & 127;
            w2cat[row * 256 + k]       = (_Float16)c2_Wl[i];
            w2cat[row * 256 + 128 + k] = (_Float16)c2_Wr[i];
        }
        for (int i = t; i < 64 * 128; i += 256) w1bf[i] = f2bf(eW1[i]);
        for (int i = t; i < 32 * 64; i += 256)  w2bf[i] = f2bf(eW2[i]);
        for (int i = t; i < 128; i += 256) {
            float s = gam[i] * rsqrtf(bvar[i] + BN_EPS);
            bnsc[i] = s;
            bnsh[i] = bet[i] - bmean[i] * s;
        }
    }
}

// Scan stage 2: per-block exclusive scan (int4 coalesced in/out) + block offset.
__global__ __launch_bounds__(256) void k_scan3(
    const int* __restrict__ deg, const int* __restrict__ part, int* __restrict__ rowptr)
{
    __shared__ int s[256];
    __shared__ int p[64];
    int t = threadIdx.x;
    int b = blockIdx.x;
    int g = b * 256 + t;
    int4 d = make_int4(0, 0, 0, 0);
    if (g < 12500) d = ((const int4*)deg)[g];
    int sum4 = d.x + d.y + d.z + d.w;
    s[t] = sum4;
    if (t < 49) p[t] = part[t];
    __syncthreads();
    #pragma unroll
    for (int off = 1; off < 256; off <<= 1) {
        int v = (t >= off) ? s[t - off] : 0;
        __syncthreads();
        s[t] += v;
        __syncthreads();
    }
    int blockoff = 0;
    for (int i = 0; i < b; ++i) blockoff += p[i];
    int off0 = blockoff + s[t] - sum4;
    if (g < 12500) {
        int4 o;
        o.x = off0;
        o.y = off0 + d.x;
        o.z = o.y + d.y;
        o.w = o.z + d.z;
        ((int4*)rowptr)[g] = o;
        if (g == 12499) rowptr[NN] = o.w + d.w;
    }
}

// Fill CSR column (src) array.
__global__ __launch_bounds__(256) void k_fill(
    const int* __restrict__ ei, const int* __restrict__ rowptr,
    int* __restrict__ cursor, int* __restrict__ csr_src)
{
    int e = blockIdx.x * blockDim.x + threadIdx.x;
    if (e >= NE) return;
    int dst = ei[NE + e];
    int slot = atomicAdd(cursor + dst, 1);
    csr_src[rowptr[dst] + slot] = ei[e];
}

// ---------------------------------------------------------------------------
// Gather-mean over CSR, fp16 in/out, f32 accumulate, 8-way unrolled.
__global__ __launch_bounds__(256) void k_gather_mean_h(
    const _Float16* __restrict__ feat, const int* __restrict__ rowptr,
    const int* __restrict__ csr_src, _Float16* __restrict__ mean)
{
    int wv = (blockIdx.x * blockDim.x + threadIdx.x) >> 6;
    int lane = threadIdx.x & 63;
    if (wv >= NN) return;
    int beg = rowptr[wv], end = rowptr[wv + 1];

    float2 a0 = {0.f, 0.f}, a1 = {0.f, 0.f}, a2 = {0.f, 0.f}, a3 = {0.f, 0.f};
    float2 a4 = {0.f, 0.f}, a5 = {0.f, 0.f}, a6 = {0.f, 0.f}, a7 = {0.f, 0.f};
    int j = beg;
    for (; j + 7 < end; j += 8) {
        int s0 = csr_src[j];
        int s1 = csr_src[j + 1];
        int s2 = csr_src[j + 2];
        int s3 = csr_src[j + 3];
        int s4 = csr_src[j + 4];
        int s5 = csr_src[j + 5];
        int s6 = csr_src[j + 6];
        int s7 = csr_src[j + 7];
        f16x2 v0 = *(const f16x2*)(feat + (size_t)s0 * 128 + lane * 2);
        f16x2 v1 = *(const f16x2*)(feat + (size_t)s1 * 128 + lane * 2);
        f16x2 v2 = *(const f16x2*)(feat + (size_t)s2 * 128 + lane * 2);
        f16x2 v3 = *(const f16x2*)(feat + (size_t)s3 * 128 + lane * 2);
        f16x2 v4 = *(const f16x2*)(feat + (size_t)s4 * 128 + lane * 2);
        f16x2 v5 = *(const f16x2*)(feat + (size_t)s5 * 128 + lane * 2);
        f16x2 v6 = *(const f16x2*)(feat + (size_t)s6 * 128 + lane * 2);
        f16x2 v7 = *(const f16x2*)(feat + (size_t)s7 * 128 + lane * 2);
        a0.x += (float)v0[0]; a0.y += (float)v0[1];
        a1.x += (float)v1[0]; a1.y += (float)v1[1];
        a2.x += (float)v2[0]; a2.y += (float)v2[1];
        a3.x += (float)v3[0]; a3.y += (float)v3[1];
        a4.x += (float)v4[0]; a4.y += (float)v4[1];
        a5.x += (float)v5[0]; a5.y += (float)v5[1];
        a6.x += (float)v6[0]; a6.y += (float)v6[1];
        a7.x += (float)v7[0]; a7.y += (float)v7[1];
    }
    for (; j + 1 < end; j += 2) {
        int s0 = csr_src[j];
        int s1 = csr_src[j + 1];
        f16x2 v0 = *(const f16x2*)(feat + (size_t)s0 * 128 + lane * 2);
        f16x2 v1 = *(const f16x2*)(feat + (size_t)s1 * 128 + lane * 2);
        a0.x += (float)v0[0]; a0.y += (float)v0[1];
        a1.x += (float)v1[0]; a1.y += (float)v1[1];
    }
    if (j < end) {
        int s0 = csr_src[j];
        f16x2 v0 = *(const f16x2*)(feat + (size_t)s0 * 128 + lane * 2);
        a0.x += (float)v0[0]; a0.y += (float)v0[1];
    }
    float inv = 1.0f / fmaxf((float)(end - beg), 1.0f);
    f16x2 o;
    o[0] = (_Float16)((a0.x + a1.x + a2.x + a3.x + a4.x + a5.x + a6.x + a7.x) * inv);
    o[1] = (_Float16)((a0.y + a1.y + a2.y + a3.y + a4.y + a5.y + a6.y + a7.y) * inv);
    *(f16x2*)(mean + (size_t)wv * 128 + lane * 2) = o;
}

// ---------------------------------------------------------------------------
// Conv1 via MFMA: h = relu(BN(mean@Wl.T + bl + x@Wr.T)), fp16 in, fp16 out.
__global__ __launch_bounds__(256) void k_conv1_mfma(
    const _Float16* __restrict__ xh, const _Float16* __restrict__ meanh,
    const _Float16* __restrict__ w1cat, const float* __restrict__ bl,
    const float* __restrict__ bnsc, const float* __restrict__ bnsh,
    _Float16* __restrict__ hh)
{
    const int tid = threadIdx.x;
    const int lane = tid & 63;
    const int e = lane & 15;
    const int c = lane >> 4;
    const int chunk = tid >> 6;
    const int tile = blockIdx.x;
    const int node = tile * 16 + e;

    f16x8 wf[2][8];
    #pragma unroll
    for (int nt = 0; nt < 2; ++nt)
        #pragma unroll
        for (int ks = 0; ks < 8; ++ks)
            wf[nt][ks] = *(const f16x8*)(w1cat + (size_t)(chunk * 32 + nt * 16 + e) * 256 + ks * 32 + c * 8);

    f32x4 acc[2];
    #pragma unroll
    for (int nt = 0; nt < 2; ++nt)
        acc[nt] = *(const f32x4*)(bl + chunk * 32 + nt * 16 + c * 4);

    f16x8 bf[8];
    #pragma unroll
    for (int ks = 0; ks < 4; ++ks)
        bf[ks] = *(const f16x8*)(meanh + (size_t)node * 128 + ks * 32 + c * 8);
    #pragma unroll
    for (int ks = 4; ks < 8; ++ks)
        bf[ks] = *(const f16x8*)(xh + (size_t)node * 128 + (ks - 4) * 32 + c * 8);

    #pragma unroll
    for (int ks = 0; ks < 8; ++ks)
        #pragma unroll
        for (int nt = 0; nt < 2; ++nt)
            acc[nt] = __builtin_amdgcn_mfma_f32_16x16x32_f16(wf[nt][ks], bf[ks], acc[nt], 0, 0, 0);

    #pragma unroll
    for (int nt = 0; nt < 2; ++nt) {
        int j0 = chunk * 32 + nt * 16 + c * 4;
        f32x4 sc = *(const f32x4*)(bnsc + j0);
        f32x4 sh = *(const f32x4*)(bnsh + j0);
        f16x4 o;
        #pragma unroll
        for (int r = 0; r < 4; ++r)
            o[r] = (_Float16)fmaxf(acc[nt][r] * sc[r] + sh[r], 0.f);
        *(f16x4*)(hh + (size_t)node * 128 + j0) = o;
    }
}

// Conv2 via MFMA: z = mean2@Wl.T + bl + h@Wr.T -> bf16.
__global__ __launch_bounds__(256) void k_conv2_mfma(
    const _Float16* __restrict__ hh, const _Float16* __restrict__ meanh,
    const _Float16* __restrict__ w2cat, const float* __restrict__ bl,
    ushort_t* __restrict__ zbf)
{
    const int tid = threadIdx.x;
    const int lane = tid & 63;
    const int e = lane & 15;
    const int c = lane >> 4;
    const int chunk = tid >> 6;
    const int tile = blockIdx.x;
    const int node = tile * 16 + e;

    f16x8 wf[8];
    #pragma unroll
    for (int ks = 0; ks < 8; ++ks)
        wf[ks] = *(const f16x8*)(w2cat + (size_t)(chunk * 16 + e) * 256 + ks * 32 + c * 8);

    f32x4 acc = *(const f32x4*)(bl + chunk * 16 + c * 4);

    f16x8 bf[8];
    #pragma unroll
    for (int ks = 0; ks < 4; ++ks)
        bf[ks] = *(const f16x8*)(meanh + (size_t)node * 128 + ks * 32 + c * 8);
    #pragma unroll
    for (int ks = 4; ks < 8; ++ks)
        bf[ks] = *(const f16x8*)(hh + (size_t)node * 128 + (ks - 4) * 32 + c * 8);

    #pragma unroll
    for (int ks = 0; ks < 8; ++ks)
        acc = __builtin_amdgcn_mfma_f32_16x16x32_f16(wf[ks], bf[ks], acc, 0, 0, 0);

    int j0 = chunk * 16 + c * 4;
    uint2 pk;
    pk.x = pk2bf(acc[0], acc[1]);
    pk.y = pk2bf(acc[2], acc[3]);
    *(uint2*)(zbf + (size_t)node * 64 + j0) = pk;
}

// ---------------------------------------------------------------------------
// Edge head via MFMA: grid-stride (12-13 tiles/wave, weights amortized) with
// 2-deep z/ep prefetch; static zA/zB buffers (rule #20).
__global__ __launch_bounds__(256) void k_edge(
    const ushort_t* __restrict__ zbf, const int* __restrict__ ep,
    const ushort_t* __restrict__ w1bf, const float* __restrict__ b1,
    const ushort_t* __restrict__ w2bf, const float* __restrict__ b2,
    const float* __restrict__ W3, const float* __restrict__ b3,
    float* __restrict__ out)
{
    __shared__ ushort_t a1lds[4][16 * 64];
    const int tid  = threadIdx.x;
    const int lane = tid & 63;
    const int e    = lane & 15;
    const int c    = lane >> 4;
    ushort_t* lds  = &a1lds[tid >> 6][0];
    const uint_t swz = (uint_t)((e & 7) << 4);

    bf16x8 w1f[4][4];
    #pragma unroll
    for (int mt = 0; mt < 4; ++mt)
        #pragma unroll
        for (int ks = 0; ks < 4; ++ks)
            w1f[mt][ks] = *(const bf16x8*)(w1bf + (mt * 16 + e) * 128 + ks * 32 + c * 8);

    bf16x8 w2f[2][2];
    #pragma unroll
    for (int mt2 = 0; mt2 < 2; ++mt2)
        #pragma unroll
        for (int ks2 = 0; ks2 < 2; ++ks2)
            w2f[mt2][ks2] = *(const bf16x8*)(w2bf + (mt2 * 16 + e) * 64 + ks2 * 32 + c * 8);

    f32x4 bias1[4];
    #pragma unroll
    for (int mt = 0; mt < 4; ++mt) bias1[mt] = *(const f32x4*)(b1 + mt * 16 + c * 4);
    f32x4 bias2[2];
    #pragma unroll
    for (int mt2 = 0; mt2 < 2; ++mt2) bias2[mt2] = *(const f32x4*)(b2 + mt2 * 16 + c * 4);
    f32x4 w3v[2];
    #pragma unroll
    for (int mt2 = 0; mt2 < 2; ++mt2) w3v[mt2] = *(const f32x4*)(W3 + mt2 * 16 + c * 4);
    const float b3v = b3[0];

    const int nw = (gridDim.x * blockDim.x) >> 6;          // 4096 waves
    const int NT = NE / 16;                                 // 50000 tiles

#define LOADZ(T, dst)                                                         \
    {                                                                         \
        int p = (T) * 16 + e;                                                 \
        int ni = ep[p];                                                       \
        int nj = ep[NE + p];                                                  \
        const ushort_t* zi = zbf + (size_t)ni * DOUT;                         \
        const ushort_t* zj = zbf + (size_t)nj * DOUT;                         \
        dst[0] = *(const bf16x8*)(zi + c * 8);                                \
        dst[1] = *(const bf16x8*)(zi + 32 + c * 8);                           \
        dst[2] = *(const bf16x8*)(zj + c * 8);                                \
        dst[3] = *(const bf16x8*)(zj + 32 + c * 8);                           \
    }

#define COMPUTE(T, bfr)                                                       \
    {                                                                         \
        f32x4 acc[4];                                                         \
        _Pragma("unroll")                                                     \
        for (int mt = 0; mt < 4; ++mt) acc[mt] = bias1[mt];                   \
        _Pragma("unroll")                                                     \
        for (int ks = 0; ks < 4; ++ks)                                        \
            _Pragma("unroll")                                                 \
            for (int mt = 0; mt < 4; ++mt)                                    \
                acc[mt] = __builtin_amdgcn_mfma_f32_16x16x32_bf16(            \
                    w1f[mt][ks], bfr[ks], acc[mt], 0, 0, 0);                  \
        _Pragma("unroll")                                                     \
        for (int mt = 0; mt < 4; ++mt) {                                      \
            uint_t lo = pk2bf(fmaxf(acc[mt][0], 0.f), fmaxf(acc[mt][1], 0.f));\
            uint_t hi = pk2bf(fmaxf(acc[mt][2], 0.f), fmaxf(acc[mt][3], 0.f));\
            uint_t off = (uint_t)(e * 128 + mt * 32 + c * 8) ^ swz;           \
            *(uint2*)((char*)lds + off) = make_uint2(lo, hi);                 \
        }                                                                     \
        bf16x8 b2f[2];                                                        \
        _Pragma("unroll")                                                     \
        for (int ks2 = 0; ks2 < 2; ++ks2) {                                   \
            uint_t off = (uint_t)(e * 128 + ks2 * 64 + c * 16) ^ swz;         \
            b2f[ks2] = *(const bf16x8*)((const char*)lds + off);              \
        }                                                                     \
        f32x4 a2[2];                                                          \
        _Pragma("unroll")                                                     \
        for (int mt2 = 0; mt2 < 2; ++mt2) a2[mt2] = bias2[mt2];               \
        _Pragma("unroll")                                                     \
        for (int ks2 = 0; ks2 < 2; ++ks2)                                     \
            _Pragma("unroll")                                                 \
            for (int mt2 = 0; mt2 < 2; ++mt2)                                 \
                a2[mt2] = __builtin_amdgcn_mfma_f32_16x16x32_bf16(            \
                    w2f[mt2][ks2], b2f[ks2], a2[mt2], 0, 0, 0);               \
        float t3 = b3v;                                                       \
        _Pragma("unroll")                                                     \
        for (int mt2 = 0; mt2 < 2; ++mt2)                                     \
            _Pragma("unroll")                                                 \
            for (int r = 0; r < 4; ++r)                                       \
                t3 += fmaxf(a2[mt2][r], 0.f) * w3v[mt2][r];                   \
        t3 += __shfl_xor(t3, 16);                                             \
        t3 += __shfl_xor(t3, 32);                                             \
        if (lane < 16) {                                                      \
            float ex = __expf(-t3);                                           \
            out[(T) * 16 + lane] = __builtin_amdgcn_rcpf(1.f + ex);           \
        }                                                                     \
    }

    bf16x8 zA[4], zB[4];
    int tile = (blockIdx.x * blockDim.x + tid) >> 6;       // first tile = wave id
    if (tile >= NT) return;
    LOADZ(tile, zA);
    while (tile < NT) {
        int nx = tile + nw;
        if (nx < NT) LOADZ(nx, zB);
        COMPUTE(tile, zA);
        tile = nx;
        if (tile >= NT) break;
        nx = tile + nw;
        if (nx < NT) LOADZ(nx, zA);
        COMPUTE(tile, zB);
        tile = nx;
    }

#undef LOADZ
#undef COMPUTE
}

// ---------------------------------------------------------------------------
extern "C" void kernel_launch(void* const* d_in, const int* in_sizes, int n_in,
                              void* d_out, int out_size, void* d_ws, size_t ws_size,
                              hipStream_t stream)
{
    const float* x     = (const float*)d_in[0];
    const int*   ei    = (const int*)d_in[1];
    const int*   ep    = (const int*)d_in[2];
    const float* c1_Wl = (const float*)d_in[3];
    const float* c1_bl = (const float*)d_in[4];
    const float* c1_Wr = (const float*)d_in[5];
    const float* bn_g  = (const float*)d_in[6];
    const float* bn_b  = (const float*)d_in[7];
    const float* bn_m  = (const float*)d_in[8];
    const float* bn_v  = (const float*)d_in[9];
    const float* c2_Wl = (const float*)d_in[10];
    const float* c2_bl = (const float*)d_in[11];
    const float* c2_Wr = (const float*)d_in[12];
    const float* e_W1  = (const float*)d_in[13];
    const float* e_b1  = (const float*)d_in[14];
    const float* e_W2  = (const float*)d_in[15];
    const float* e_b2  = (const float*)d_in[16];
    const float* e_W3  = (const float*)d_in[17];
    const float* e_b3  = (const float*)d_in[18];
    float* out = (float*)d_out;

    _Float16* xh    = (_Float16*)d_ws;
    _Float16* meanh = xh + (size_t)NN * DIN;
    _Float16* hh    = meanh + (size_t)NN * DIN;
    ushort_t* zbf   = (ushort_t*)(hh + (size_t)NN * DHID);
    _Float16* w1cat = (_Float16*)(zbf + (size_t)NN * DOUT);
    _Float16* w2cat = w1cat + 128 * 256;
    ushort_t* w1bf  = (ushort_t*)(w2cat + 64 * 256);
    ushort_t* w2bf  = w1bf + 64 * 128;
    float*    bnsc  = (float*)(w2bf + 32 * 64);
    float*    bnsh  = bnsc + 128;
    int*      deg     = (int*)(bnsh + 128);
    int*      cursor  = deg + 50048;
    int*      rowptr  = cursor + 50048;
    int*      csr_src = rowptr + 50052;
    int*      part    = csr_src + 800000;

    hipMemsetAsync(deg, 0, (size_t)(50048 * 2) * sizeof(int), stream);

    k_deg_xcast<<<6250, 256, 0, stream>>>(ei, deg, x, xh);
    k_scan1_prep<<<50, 256, 0, stream>>>(deg, part,
                                         c1_Wl, c1_Wr, c2_Wl, c2_Wr,
                                         bn_g, bn_b, bn_m, bn_v, e_W1, e_W2,
                                         w1cat, w2cat, w1bf, w2bf, bnsc, bnsh);
    k_scan3<<<49, 256, 0, stream>>>(deg, part, rowptr);
    k_fill <<<3125, 256, 0, stream>>>(ei, rowptr, cursor, csr_src);

    k_gather_mean_h<<<12500, 256, 0, stream>>>(xh, rowptr, csr_src, meanh);
    k_conv1_mfma<<<3125, 256, 0, stream>>>(xh, meanh, w1cat, c1_bl, bnsc, bnsh, hh);

    k_gather_mean_h<<<12500, 256, 0, stream>>>(hh, rowptr, csr_src, meanh);
    k_conv2_mfma<<<3125, 256, 0, stream>>>(hh, meanh, w2cat, c2_bl, zbf);

    k_edge<<<1024, 256, 0, stream>>>(zbf, ep, w1bf, e_b1, w2bf, e_b2,
                                     e_W3, e_b3, out);
}

// Round 10
// 295.724 us; speedup vs baseline: 12.1790x; 1.0248x over previous
//
#include <hip/hip_runtime.h>
#include <hip/hip_bf16.h>
#include <math.h>

#define NN 50000
#define NE 800000
#define DIN 128
#define DHID 128
#define DOUT 64
#define BN_EPS 1e-5f

typedef __attribute__((ext_vector_type(8))) short bf16x8;
typedef __attribute__((ext_vector_type(8))) _Float16 f16x8;
typedef __attribute__((ext_vector_type(4))) _Float16 f16x4;
typedef __attribute__((ext_vector_type(2))) _Float16 f16x2;
typedef __attribute__((ext_vector_type(4))) float f32x4;
typedef unsigned short ushort_t;
typedef unsigned int uint_t;

__device__ __forceinline__ ushort_t f2bf(float f) {
    uint_t u = __float_as_uint(f);
    uint_t r = (u + 0x7FFFu + ((u >> 16) & 1u)) >> 16;   // RNE
    return (ushort_t)r;
}

__device__ __forceinline__ uint_t pk2bf(float a, float b) {
    __hip_bfloat16 x = __float2bfloat16(a);
    __hip_bfloat16 y = __float2bfloat16(b);
    ushort_t ux = *reinterpret_cast<ushort_t*>(&x);
    ushort_t uy = *reinterpret_cast<ushort_t*>(&y);
    return (uint_t)ux | ((uint_t)uy << 16);
}

// ---------------------------------------------------------------------------
// Fused: blocks [0,3125) histogram dst degrees; blocks [3125,6250) cast x->fp16.
__global__ __launch_bounds__(256) void k_deg_xcast(
    const int* __restrict__ ei, int* __restrict__ deg,
    const float* __restrict__ x, _Float16* __restrict__ xh)
{
    int b = blockIdx.x;
    if (b < 3125) {
        int e = b * 256 + threadIdx.x;
        atomicAdd(deg + ei[NE + e], 1);
    } else {
        int i = (b - 3125) * 256 + threadIdx.x;
        const float4* src = (const float4*)x + (size_t)i * 2;
        float4 a = src[0], c = src[1];
        f16x8 o;
        o[0] = (_Float16)a.x; o[1] = (_Float16)a.y; o[2] = (_Float16)a.z; o[3] = (_Float16)a.w;
        o[4] = (_Float16)c.x; o[5] = (_Float16)c.y; o[6] = (_Float16)c.z; o[7] = (_Float16)c.w;
        *(f16x8*)(xh + (size_t)i * 8) = o;
    }
}

// ---------------------------------------------------------------------------
// Scan stage 1 (blocks 0..48) + weight prep (block 49).
__global__ __launch_bounds__(256) void k_scan1_prep(
    const int* __restrict__ deg, int* __restrict__ part,
    const float* __restrict__ c1_Wl, const float* __restrict__ c1_Wr,
    const float* __restrict__ c2_Wl, const float* __restrict__ c2_Wr,
    const float* __restrict__ gam, const float* __restrict__ bet,
    const float* __restrict__ bmean, const float* __restrict__ bvar,
    const float* __restrict__ eW1, const float* __restrict__ eW2,
    _Float16* __restrict__ w1cat, _Float16* __restrict__ w2cat,
    ushort_t* __restrict__ w1bf, ushort_t* __restrict__ w2bf,
    float* __restrict__ bnsc, float* __restrict__ bnsh)
{
    int t = threadIdx.x;
    if (blockIdx.x < 49) {
        __shared__ int s[256];
        int g = blockIdx.x * 256 + t;
        int v = 0;
        if (g < 12500) { int4 d = ((const int4*)deg)[g]; v = d.x + d.y + d.z + d.w; }
        s[t] = v;
        __syncthreads();
        #pragma unroll
        for (int off = 128; off > 0; off >>= 1) {
            if (t < off) s[t] += s[t + off];
            __syncthreads();
        }
        if (t == 0) part[blockIdx.x] = s[0];
    } else {
        for (int i = t; i < 128 * 128; i += 256) {
            int row = i >> 7, k = i & 127;
            w1cat[row * 256 + k]       = (_Float16)c1_Wl[i];
            w1cat[row * 256 + 128 + k] = (_Float16)c1_Wr[i];
        }
        for (int i = t; i < 64 * 128; i += 256) {
            int row = i >> 7, k = i & 127;
            w2cat[row * 256 + k]       = (_Float16)c2_Wl[i];
            w2cat[row * 256 + 128 + k] = (_Float16)c2_Wr[i];
        }
        for (int i = t; i < 64 * 128; i += 256) w1bf[i] = f2bf(eW1[i]);
        for (int i = t; i < 32 * 64; i += 256)  w2bf[i] = f2bf(eW2[i]);
        for (int i = t; i < 128; i += 256) {
            float s = gam[i] * rsqrtf(bvar[i] + BN_EPS);
            bnsc[i] = s;
            bnsh[i] = bet[i] - bmean[i] * s;
        }
    }
}

// Scan stage 2: per-block exclusive scan + block offset.
__global__ __launch_bounds__(256) void k_scan3(
    const int* __restrict__ deg, const int* __restrict__ part, int* __restrict__ rowptr)
{
    __shared__ int s[256];
    __shared__ int p[64];
    int t = threadIdx.x;
    int b = blockIdx.x;
    int g = b * 256 + t;
    int4 d = make_int4(0, 0, 0, 0);
    if (g < 12500) d = ((const int4*)deg)[g];
    int sum4 = d.x + d.y + d.z + d.w;
    s[t] = sum4;
    if (t < 49) p[t] = part[t];
    __syncthreads();
    #pragma unroll
    for (int off = 1; off < 256; off <<= 1) {
        int v = (t >= off) ? s[t - off] : 0;
        __syncthreads();
        s[t] += v;
        __syncthreads();
    }
    int blockoff = 0;
    for (int i = 0; i < b; ++i) blockoff += p[i];
    int off0 = blockoff + s[t] - sum4;
    if (g < 12500) {
        int4 o;
        o.x = off0;
        o.y = off0 + d.x;
        o.z = o.y + d.y;
        o.w = o.z + d.z;
        ((int4*)rowptr)[g] = o;
        if (g == 12499) rowptr[NN] = o.w + d.w;
    }
}

// Fill CSR column (src) array.
__global__ __launch_bounds__(256) void k_fill(
    const int* __restrict__ ei, const int* __restrict__ rowptr,
    int* __restrict__ cursor, int* __restrict__ csr_src)
{
    int e = blockIdx.x * blockDim.x + threadIdx.x;
    if (e >= NE) return;
    int dst = ei[NE + e];
    int slot = atomicAdd(cursor + dst, 1);
    csr_src[rowptr[dst] + slot] = ei[e];
}

// ---------------------------------------------------------------------------
// GATHER macro: wave gathers 4 nodes' means into swizzled LDS tile.
// mlds byte layout: node n row at n*256, 4B/lane, XOR swizzle ((n&7)<<4).
#define GATHER4(feat)                                                          \
    {                                                                          \
        _Pragma("unroll 1")                                                    \
        for (int q = 0; q < 4; ++q) {                                          \
            int n = w * 4 + q;                                                 \
            int node = tile * 16 + n;                                          \
            int beg = __builtin_amdgcn_readfirstlane(rowptr[node]);            \
            int end = __builtin_amdgcn_readfirstlane(rowptr[node + 1]);        \
            float2 a0 = {0.f,0.f}, a1 = {0.f,0.f}, a2 = {0.f,0.f}, a3 = {0.f,0.f}; \
            float2 a4 = {0.f,0.f}, a5 = {0.f,0.f}, a6 = {0.f,0.f}, a7 = {0.f,0.f}; \
            int j = beg;                                                       \
            for (; j + 7 < end; j += 8) {                                      \
                int s0 = csr_src[j];     int s1 = csr_src[j + 1];              \
                int s2 = csr_src[j + 2]; int s3 = csr_src[j + 3];              \
                int s4 = csr_src[j + 4]; int s5 = csr_src[j + 5];              \
                int s6 = csr_src[j + 6]; int s7 = csr_src[j + 7];              \
                f16x2 v0 = *(const f16x2*)(feat + (size_t)s0 * 128 + lane * 2);\
                f16x2 v1 = *(const f16x2*)(feat + (size_t)s1 * 128 + lane * 2);\
                f16x2 v2 = *(const f16x2*)(feat + (size_t)s2 * 128 + lane * 2);\
                f16x2 v3 = *(const f16x2*)(feat + (size_t)s3 * 128 + lane * 2);\
                f16x2 v4 = *(const f16x2*)(feat + (size_t)s4 * 128 + lane * 2);\
                f16x2 v5 = *(const f16x2*)(feat + (size_t)s5 * 128 + lane * 2);\
                f16x2 v6 = *(const f16x2*)(feat + (size_t)s6 * 128 + lane * 2);\
                f16x2 v7 = *(const f16x2*)(feat + (size_t)s7 * 128 + lane * 2);\
                a0.x += (float)v0[0]; a0.y += (float)v0[1];                    \
                a1.x += (float)v1[0]; a1.y += (float)v1[1];                    \
                a2.x += (float)v2[0]; a2.y += (float)v2[1];                    \
                a3.x += (float)v3[0]; a3.y += (float)v3[1];                    \
                a4.x += (float)v4[0]; a4.y += (float)v4[1];                    \
                a5.x += (float)v5[0]; a5.y += (float)v5[1];                    \
                a6.x += (float)v6[0]; a6.y += (float)v6[1];                    \
                a7.x += (float)v7[0]; a7.y += (float)v7[1];                    \
            }                                                                  \
            for (; j + 1 < end; j += 2) {                                      \
                int s0 = csr_src[j];                                           \
                int s1 = csr_src[j + 1];                                       \
                f16x2 v0 = *(const f16x2*)(feat + (size_t)s0 * 128 + lane * 2);\
                f16x2 v1 = *(const f16x2*)(feat + (size_t)s1 * 128 + lane * 2);\
                a0.x += (float)v0[0]; a0.y += (float)v0[1];                    \
                a1.x += (float)v1[0]; a1.y += (float)v1[1];                    \
            }                                                                  \
            if (j < end) {                                                     \
                int s0 = csr_src[j];                                           \
                f16x2 v0 = *(const f16x2*)(feat + (size_t)s0 * 128 + lane * 2);\
                a0.x += (float)v0[0]; a0.y += (float)v0[1];                    \
            }                                                                  \
            float inv = 1.0f / fmaxf((float)(end - beg), 1.0f);                \
            f16x2 o;                                                           \
            o[0] = (_Float16)((a0.x + a1.x + a2.x + a3.x + a4.x + a5.x + a6.x + a7.x) * inv); \
            o[1] = (_Float16)((a0.y + a1.y + a2.y + a3.y + a4.y + a5.y + a6.y + a7.y) * inv); \
            uint_t off = (uint_t)(n * 256 + lane * 4) ^ (uint_t)((n & 7) << 4);\
            *(f16x2*)((char*)mlds + off) = o;                                  \
        }                                                                      \
    }

// Fused gather-mean + Conv1 (MFMA): h = relu(BN(mean@Wl.T + bl + x@Wr.T)).
__global__ __launch_bounds__(256) void k_gconv1(
    const _Float16* __restrict__ xh, const int* __restrict__ rowptr,
    const int* __restrict__ csr_src,
    const _Float16* __restrict__ w1cat, const float* __restrict__ bl,
    const float* __restrict__ bnsc, const float* __restrict__ bnsh,
    _Float16* __restrict__ hh)
{
    __shared__ _Float16 mlds[16 * 128];   // 4 KB, swizzled
    const int tid = threadIdx.x;
    const int lane = tid & 63;
    const int w = tid >> 6;               // wave = col-chunk AND gather group
    const int tile = blockIdx.x;          // 3125 * 16 nodes
    const int e = lane & 15;
    const int c = lane >> 4;
    const int node = tile * 16 + e;

    // issue weight + x-feature loads first; latency hides under the gather
    f16x8 wf[2][8];
    #pragma unroll
    for (int nt = 0; nt < 2; ++nt)
        #pragma unroll
        for (int ks = 0; ks < 8; ++ks)
            wf[nt][ks] = *(const f16x8*)(w1cat + (size_t)(w * 32 + nt * 16 + e) * 256 + ks * 32 + c * 8);
    f16x8 bfx[4];
    #pragma unroll
    for (int ks = 0; ks < 4; ++ks)
        bfx[ks] = *(const f16x8*)(xh + (size_t)node * 128 + ks * 32 + c * 8);
    f32x4 acc[2];
    #pragma unroll
    for (int nt = 0; nt < 2; ++nt)
        acc[nt] = *(const f32x4*)(bl + w * 32 + nt * 16 + c * 4);

    GATHER4(xh);
    __syncthreads();

    f16x8 bfm[4];
    #pragma unroll
    for (int ks = 0; ks < 4; ++ks) {
        uint_t off = (uint_t)(e * 256 + ks * 64 + c * 16) ^ (uint_t)((e & 7) << 4);
        bfm[ks] = *(const f16x8*)((const char*)mlds + off);
    }

    #pragma unroll
    for (int ks = 0; ks < 4; ++ks)
        #pragma unroll
        for (int nt = 0; nt < 2; ++nt)
            acc[nt] = __builtin_amdgcn_mfma_f32_16x16x32_f16(wf[nt][ks], bfm[ks], acc[nt], 0, 0, 0);
    #pragma unroll
    for (int ks = 0; ks < 4; ++ks)
        #pragma unroll
        for (int nt = 0; nt < 2; ++nt)
            acc[nt] = __builtin_amdgcn_mfma_f32_16x16x32_f16(wf[nt][ks + 4], bfx[ks], acc[nt], 0, 0, 0);

    #pragma unroll
    for (int nt = 0; nt < 2; ++nt) {
        int j0 = w * 32 + nt * 16 + c * 4;
        f32x4 sc = *(const f32x4*)(bnsc + j0);
        f32x4 sh = *(const f32x4*)(bnsh + j0);
        f16x4 o;
        #pragma unroll
        for (int r = 0; r < 4; ++r)
            o[r] = (_Float16)fmaxf(acc[nt][r] * sc[r] + sh[r], 0.f);
        *(f16x4*)(hh + (size_t)node * 128 + j0) = o;
    }
}

// Fused gather-mean + Conv2 (MFMA): z = mean2@Wl.T + bl + h@Wr.T -> bf16.
__global__ __launch_bounds__(256) void k_gconv2(
    const _Float16* __restrict__ hh, const int* __restrict__ rowptr,
    const int* __restrict__ csr_src,
    const _Float16* __restrict__ w2cat, const float* __restrict__ bl,
    ushort_t* __restrict__ zbf)
{
    __shared__ _Float16 mlds[16 * 128];
    const int tid = threadIdx.x;
    const int lane = tid & 63;
    const int w = tid >> 6;
    const int tile = blockIdx.x;
    const int e = lane & 15;
    const int c = lane >> 4;
    const int node = tile * 16 + e;

    f16x8 wf[8];
    #pragma unroll
    for (int ks = 0; ks < 8; ++ks)
        wf[ks] = *(const f16x8*)(w2cat + (size_t)(w * 16 + e) * 256 + ks * 32 + c * 8);
    f16x8 bfx[4];
    #pragma unroll
    for (int ks = 0; ks < 4; ++ks)
        bfx[ks] = *(const f16x8*)(hh + (size_t)node * 128 + ks * 32 + c * 8);
    f32x4 acc = *(const f32x4*)(bl + w * 16 + c * 4);

    GATHER4(hh);
    __syncthreads();

    f16x8 bfm[4];
    #pragma unroll
    for (int ks = 0; ks < 4; ++ks) {
        uint_t off = (uint_t)(e * 256 + ks * 64 + c * 16) ^ (uint_t)((e & 7) << 4);
        bfm[ks] = *(const f16x8*)((const char*)mlds + off);
    }

    #pragma unroll
    for (int ks = 0; ks < 4; ++ks)
        acc = __builtin_amdgcn_mfma_f32_16x16x32_f16(wf[ks], bfm[ks], acc, 0, 0, 0);
    #pragma unroll
    for (int ks = 0; ks < 4; ++ks)
        acc = __builtin_amdgcn_mfma_f32_16x16x32_f16(wf[ks + 4], bfx[ks], acc, 0, 0, 0);

    int j0 = w * 16 + c * 4;
    uint2 pk;
    pk.x = pk2bf(acc[0], acc[1]);
    pk.y = pk2bf(acc[2], acc[3]);
    *(uint2*)(zbf + (size_t)node * 64 + j0) = pk;
}

// ---------------------------------------------------------------------------
// Edge head via MFMA: grid-stride with 2-deep z/ep prefetch + setprio on MFMA.
__global__ __launch_bounds__(256) void k_edge(
    const ushort_t* __restrict__ zbf, const int* __restrict__ ep,
    const ushort_t* __restrict__ w1bf, const float* __restrict__ b1,
    const ushort_t* __restrict__ w2bf, const float* __restrict__ b2,
    const float* __restrict__ W3, const float* __restrict__ b3,
    float* __restrict__ out)
{
    __shared__ ushort_t a1lds[4][16 * 64];
    const int tid  = threadIdx.x;
    const int lane = tid & 63;
    const int e    = lane & 15;
    const int c    = lane >> 4;
    ushort_t* lds  = &a1lds[tid >> 6][0];
    const uint_t swz = (uint_t)((e & 7) << 4);

    bf16x8 w1f[4][4];
    #pragma unroll
    for (int mt = 0; mt < 4; ++mt)
        #pragma unroll
        for (int ks = 0; ks < 4; ++ks)
            w1f[mt][ks] = *(const bf16x8*)(w1bf + (mt * 16 + e) * 128 + ks * 32 + c * 8);

    bf16x8 w2f[2][2];
    #pragma unroll
    for (int mt2 = 0; mt2 < 2; ++mt2)
        #pragma unroll
        for (int ks2 = 0; ks2 < 2; ++ks2)
            w2f[mt2][ks2] = *(const bf16x8*)(w2bf + (mt2 * 16 + e) * 64 + ks2 * 32 + c * 8);

    f32x4 bias1[4];
    #pragma unroll
    for (int mt = 0; mt < 4; ++mt) bias1[mt] = *(const f32x4*)(b1 + mt * 16 + c * 4);
    f32x4 bias2[2];
    #pragma unroll
    for (int mt2 = 0; mt2 < 2; ++mt2) bias2[mt2] = *(const f32x4*)(b2 + mt2 * 16 + c * 4);
    f32x4 w3v[2];
    #pragma unroll
    for (int mt2 = 0; mt2 < 2; ++mt2) w3v[mt2] = *(const f32x4*)(W3 + mt2 * 16 + c * 4);
    const float b3v = b3[0];

    const int nw = (gridDim.x * blockDim.x) >> 6;
    const int NT = NE / 16;

#define LOADZ(T, dst)                                                         \
    {                                                                         \
        int p = (T) * 16 + e;                                                 \
        int ni = ep[p];                                                       \
        int nj = ep[NE + p];                                                  \
        const ushort_t* zi = zbf + (size_t)ni * DOUT;                         \
        const ushort_t* zj = zbf + (size_t)nj * DOUT;                         \
        dst[0] = *(const bf16x8*)(zi + c * 8);                                \
        dst[1] = *(const bf16x8*)(zi + 32 + c * 8);                           \
        dst[2] = *(const bf16x8*)(zj + c * 8);                                \
        dst[3] = *(const bf16x8*)(zj + 32 + c * 8);                           \
    }

#define COMPUTE(T, bfr)                                                       \
    {                                                                         \
        f32x4 acc[4];                                                         \
        _Pragma("unroll")                                                     \
        for (int mt = 0; mt < 4; ++mt) acc[mt] = bias1[mt];                   \
        __builtin_amdgcn_s_setprio(1);                                        \
        _Pragma("unroll")                                                     \
        for (int ks = 0; ks < 4; ++ks)                                        \
            _Pragma("unroll")                                                 \
            for (int mt = 0; mt < 4; ++mt)                                    \
                acc[mt] = __builtin_amdgcn_mfma_f32_16x16x32_bf16(            \
                    w1f[mt][ks], bfr[ks], acc[mt], 0, 0, 0);                  \
        __builtin_amdgcn_s_setprio(0);                                        \
        _Pragma("unroll")                                                     \
        for (int mt = 0; mt < 4; ++mt) {                                      \
            uint_t lo = pk2bf(fmaxf(acc[mt][0], 0.f), fmaxf(acc[mt][1], 0.f));\
            uint_t hi = pk2bf(fmaxf(acc[mt][2], 0.f), fmaxf(acc[mt][3], 0.f));\
            uint_t off = (uint_t)(e * 128 + mt * 32 + c * 8) ^ swz;           \
            *(uint2*)((char*)lds + off) = make_uint2(lo, hi);                 \
        }                                                                     \
        bf16x8 b2f[2];                                                        \
        _Pragma("unroll")                                                     \
        for (int ks2 = 0; ks2 < 2; ++ks2) {                                   \
            uint_t off = (uint_t)(e * 128 + ks2 * 64 + c * 16) ^ swz;         \
            b2f[ks2] = *(const bf16x8*)((const char*)lds + off);              \
        }                                                                     \
        f32x4 a2[2];                                                          \
        _Pragma("unroll")                                                     \
        for (int mt2 = 0; mt2 < 2; ++mt2) a2[mt2] = bias2[mt2];               \
        __builtin_amdgcn_s_setprio(1);                                        \
        _Pragma("unroll")                                                     \
        for (int ks2 = 0; ks2 < 2; ++ks2)                                     \
            _Pragma("unroll")                                                 \
            for (int mt2 = 0; mt2 < 2; ++mt2)                                 \
                a2[mt2] = __builtin_amdgcn_mfma_f32_16x16x32_bf16(            \
                    w2f[mt2][ks2], b2f[ks2], a2[mt2], 0, 0, 0);               \
        __builtin_amdgcn_s_setprio(0);                                        \
        float t3 = b3v;                                                       \
        _Pragma("unroll")                                                     \
        for (int mt2 = 0; mt2 < 2; ++mt2)                                     \
            _Pragma("unroll")                                                 \
            for (int r = 0; r < 4; ++r)                                       \
                t3 += fmaxf(a2[mt2][r], 0.f) * w3v[mt2][r];                   \
        t3 += __shfl_xor(t3, 16);                                             \
        t3 += __shfl_xor(t3, 32);                                             \
        if (lane < 16) {                                                      \
            float ex = __expf(-t3);                                           \
            out[(T) * 16 + lane] = __builtin_amdgcn_rcpf(1.f + ex);           \
        }                                                                     \
    }

    bf16x8 zA[4], zB[4];
    int tile = (blockIdx.x * blockDim.x + tid) >> 6;
    if (tile >= NT) return;
    LOADZ(tile, zA);
    while (tile < NT) {
        int nx = tile + nw;
        if (nx < NT) LOADZ(nx, zB);
        COMPUTE(tile, zA);
        tile = nx;
        if (tile >= NT) break;
        nx = tile + nw;
        if (nx < NT) LOADZ(nx, zA);
        COMPUTE(tile, zB);
        tile = nx;
    }

#undef LOADZ
#undef COMPUTE
}

// ---------------------------------------------------------------------------
extern "C" void kernel_launch(void* const* d_in, const int* in_sizes, int n_in,
                              void* d_out, int out_size, void* d_ws, size_t ws_size,
                              hipStream_t stream)
{
    const float* x     = (const float*)d_in[0];
    const int*   ei    = (const int*)d_in[1];
    const int*   ep    = (const int*)d_in[2];
    const float* c1_Wl = (const float*)d_in[3];
    const float* c1_bl = (const float*)d_in[4];
    const float* c1_Wr = (const float*)d_in[5];
    const float* bn_g  = (const float*)d_in[6];
    const float* bn_b  = (const float*)d_in[7];
    const float* bn_m  = (const float*)d_in[8];
    const float* bn_v  = (const float*)d_in[9];
    const float* c2_Wl = (const float*)d_in[10];
    const float* c2_bl = (const float*)d_in[11];
    const float* c2_Wr = (const float*)d_in[12];
    const float* e_W1  = (const float*)d_in[13];
    const float* e_b1  = (const float*)d_in[14];
    const float* e_W2  = (const float*)d_in[15];
    const float* e_b2  = (const float*)d_in[16];
    const float* e_W3  = (const float*)d_in[17];
    const float* e_b3  = (const float*)d_in[18];
    float* out = (float*)d_out;

    _Float16* xh    = (_Float16*)d_ws;
    _Float16* meanh = xh + (size_t)NN * DIN;     // unused (kept for layout stability)
    _Float16* hh    = meanh + (size_t)NN * DIN;
    ushort_t* zbf   = (ushort_t*)(hh + (size_t)NN * DHID);
    _Float16* w1cat = (_Float16*)(zbf + (size_t)NN * DOUT);
    _Float16* w2cat = w1cat + 128 * 256;
    ushort_t* w1bf  = (ushort_t*)(w2cat + 64 * 256);
    ushort_t* w2bf  = w1bf + 64 * 128;
    float*    bnsc  = (float*)(w2bf + 32 * 64);
    float*    bnsh  = bnsc + 128;
    int*      deg     = (int*)(bnsh + 128);
    int*      cursor  = deg + 50048;
    int*      rowptr  = cursor + 50048;
    int*      csr_src = rowptr + 50052;
    int*      part    = csr_src + 800000;

    hipMemsetAsync(deg, 0, (size_t)(50048 * 2) * sizeof(int), stream);

    k_deg_xcast<<<6250, 256, 0, stream>>>(ei, deg, x, xh);
    k_scan1_prep<<<50, 256, 0, stream>>>(deg, part,
                                         c1_Wl, c1_Wr, c2_Wl, c2_Wr,
                                         bn_g, bn_b, bn_m, bn_v, e_W1, e_W2,
                                         w1cat, w2cat, w1bf, w2bf, bnsc, bnsh);
    k_scan3<<<49, 256, 0, stream>>>(deg, part, rowptr);
    k_fill <<<3125, 256, 0, stream>>>(ei, rowptr, cursor, csr_src);

    k_gconv1<<<3125, 256, 0, stream>>>(xh, rowptr, csr_src, w1cat, c1_bl, bnsc, bnsh, hh);
    k_gconv2<<<3125, 256, 0, stream>>>(hh, rowptr, csr_src, w2cat, c2_bl, zbf);

    k_edge<<<1280, 256, 0, stream>>>(zbf, ep, w1bf, e_b1, w2bf, e_b2,
                                     e_W3, e_b3, out);
}